// Round 11
// baseline (401.024 us; speedup 1.0000x reference)
//
#include <hip/hip_runtime.h>
#include <hip/hip_bf16.h>
#include <math.h>

typedef __hip_bfloat16 bf16;
typedef __attribute__((ext_vector_type(8))) short short8;
typedef __attribute__((ext_vector_type(4))) float f32x4;

#define D_  768
#define H_  12
#define HD_ 64
#define F_  3072
#define B_  4
#define S_  2048
#define BS_ (B_*S_)
#define SQK 1536   // Q,K buffer row stride (V lives in packed Vp)
#define PSTR 72    // P LDS row stride in u16 (64 + 8 pad; 144 B = 16B-aligned rows)

__device__ __forceinline__ float b2f(bf16 x){ return __bfloat162float(x); }

union BU { bf16 b; unsigned short u; };
// fast bf16 round (half-away ties; inputs are finite, non-NaN)
__device__ __forceinline__ bf16 f2b_fast(float x){
  BU t; t.u = (unsigned short)((__float_as_uint(x) + 0x8000u) >> 16); return t.b;
}
// pack two floats -> bf16x2 dword (low u16 = a)
__device__ __forceinline__ unsigned pk2bf(float a, float b){
  return __builtin_amdgcn_perm(__float_as_uint(b) + 0x8000u,
                               __float_as_uint(a) + 0x8000u, 0x07060302u);
}

__device__ __forceinline__ f32x4 zero4(){ f32x4 z; z.x=0.f; z.y=0.f; z.z=0.f; z.w=0.f; return z; }

__device__ __forceinline__ f32x4 mfma16(uint4 a, uint4 b, f32x4 c){
  union U { uint4 u; short8 s; };
  U A, B; A.u = a; B.u = b;
  return __builtin_amdgcn_mfma_f32_16x16x32_bf16(A.s, B.s, c, 0, 0, 0);
}

// async global->LDS, 16 B per lane (global_load_lds_dwordx4)
typedef const __attribute__((address_space(1))) void gvoid;
typedef __attribute__((address_space(3))) void lvoid;
__device__ __forceinline__ void load_lds16(const void* g, void* l){
  __builtin_amdgcn_global_load_lds((gvoid*)g, (lvoid*)l, 16, 0, 0);
}

// exact-accuracy GELU via A&S 7.1.26 erf (|eps| <= 1.5e-7), HW exp/rcp
__device__ __forceinline__ float fast_gelu(float v){
  const float x = v * 0.70710678118654752f;
  const float ax = fabsf(x);
  const float t = __builtin_amdgcn_rcpf(fmaf(0.3275911f, ax, 1.0f));
  const float poly = t * fmaf(t, fmaf(t, fmaf(t, fmaf(t, 1.061405429f, -1.453152027f),
                                              1.421413741f), -0.284496736f), 0.254829592f);
  const float e = __builtin_amdgcn_exp2f(ax * ax * -1.4426950408889634f);
  const float erfax = 1.0f - poly * e;
  const float erfx = copysignf(erfax, x);
  return 0.5f * v * (1.0f + erfx);
}

// ---------------- weight repack (fp32 -> bf16 W^T): Wt[n][k] = W[k][n] -------------
__global__ __launch_bounds__(256)
void repack_t(const float* __restrict__ W, bf16* __restrict__ Wt, int K, int N)
{
  const int t = blockIdx.x * 256 + threadIdx.x;   // exact grids
  const int n = t % N;
  const int kg = t / N;
  const float* src = W + (size_t)kg * 8 * N + n;
  union { unsigned u32[4]; uint4 u; } pk;
#pragma unroll
  for (int j = 0; j < 4; ++j)
    pk.u32[j] = pk2bf(src[(size_t)(2 * j) * N], src[(size_t)(2 * j + 1) * N]);
  *(uint4*)(Wt + ((size_t)n * (K >> 3) + kg) * 8) = pk.u;
}

// QKV combined W^T: rows n in [0,2304): sel=n/768, h=(n%768)>>6, e=n&63; K=768
__global__ __launch_bounds__(256)
void repack_qkv_t(const float* __restrict__ Wq, const float* __restrict__ Wk,
                  const float* __restrict__ Wv, bf16* __restrict__ Wt)
{
  const int t = blockIdx.x * 256 + threadIdx.x;   // 864*256 = 96*2304 exact
  const int n = t % 2304;
  const int kg = t / 2304;                        // 0..95
  const int sel = n / 768;
  const int nn = n - sel * 768;
  const int hh = nn >> 6;
  const int ee = nn & 63;
  const float* W = (sel == 0) ? Wq : (sel == 1) ? Wk : Wv;
  const float* src = W + ((size_t)hh * 768 + (size_t)kg * 8) * 64 + ee;
  union { unsigned u32[4]; uint4 u; } pk;
#pragma unroll
  for (int j = 0; j < 4; ++j)
    pk.u32[j] = pk2bf(src[(size_t)(2 * j) * 64], src[(size_t)(2 * j + 1) * 64]);
  *(uint4*)(Wt + ((size_t)n * 96 + kg) * 8) = pk.u;
}

__global__ __launch_bounds__(256)
void bias_qkv(const float* __restrict__ bq, const float* __restrict__ bk,
              const float* __restrict__ bv, float* __restrict__ out)
{
  const int t = blockIdx.x * 256 + threadIdx.x;   // 9*256 = 2304 exact
  out[t] = (t < 768) ? bq[t] : (t < 1536) ? bk[t - 768] : bv[t - 1536];
}

// ---------------- LayerNorm: one block per token, 256 thr, D=768=256*3 ----------------
__global__ __launch_bounds__(256)
void ln_x_kernel(const float* __restrict__ X, const float* __restrict__ G,
                 const float* __restrict__ Bet, bf16* __restrict__ Y)
{
  const int t = threadIdx.x;
  const size_t row = blockIdx.x;
  const float* x = X + row * D_;
  float v0 = x[t], v1 = x[t + 256], v2 = x[t + 512];
  float s = v0 + v1 + v2;
#pragma unroll
  for (int d = 32; d >= 1; d >>= 1) s += __shfl_xor(s, d, 64);
  __shared__ float red[8];
  const int wv = t >> 6, ln = t & 63;
  if (ln == 0) red[wv] = s;
  __syncthreads();
  const float mu = (red[0] + red[1] + red[2] + red[3]) * (1.0f / 768.0f);
  const float d0 = v0 - mu, d1 = v1 - mu, d2 = v2 - mu;
  float sq = d0 * d0 + d1 * d1 + d2 * d2;
#pragma unroll
  for (int d = 32; d >= 1; d >>= 1) sq += __shfl_xor(sq, d, 64);
  if (ln == 0) red[4 + wv] = sq;
  __syncthreads();
  const float var = (red[4] + red[5] + red[6] + red[7]) * (1.0f / 768.0f);
  const float rs = rsqrtf(var + 1e-5f);
  bf16* y = Y + row * D_;
  y[t]       = f2b_fast(d0 * rs * G[t]       + Bet[t]);
  y[t + 256] = f2b_fast(d1 * rs * G[t + 256] + Bet[t + 256]);
  y[t + 512] = f2b_fast(d2 * rs * G[t + 512] + Bet[t + 512]);
}

// LN over bf16 input:
__global__ __launch_bounds__(256)
void ln_h_kernel(const bf16* __restrict__ X, const float* __restrict__ G,
                 const float* __restrict__ Bet, bf16* __restrict__ Y)
{
  const int t = threadIdx.x;
  const size_t row = blockIdx.x;
  const bf16* x = X + row * D_;
  float v0 = b2f(x[t]), v1 = b2f(x[t + 256]), v2 = b2f(x[t + 512]);
  float s = v0 + v1 + v2;
#pragma unroll
  for (int d = 32; d >= 1; d >>= 1) s += __shfl_xor(s, d, 64);
  __shared__ float red[8];
  const int wv = t >> 6, ln = t & 63;
  if (ln == 0) red[wv] = s;
  __syncthreads();
  const float mu = (red[0] + red[1] + red[2] + red[3]) * (1.0f / 768.0f);
  const float d0 = v0 - mu, d1 = v1 - mu, d2 = v2 - mu;
  float sq = d0 * d0 + d1 * d1 + d2 * d2;
#pragma unroll
  for (int d = 32; d >= 1; d >>= 1) sq += __shfl_xor(sq, d, 64);
  if (ln == 0) red[4 + wv] = sq;
  __syncthreads();
  const float var = (red[4] + red[5] + red[6] + red[7]) * (1.0f / 768.0f);
  const float rs = rsqrtf(var + 1e-5f);
  bf16* y = Y + row * D_;
  y[t]       = f2b_fast(d0 * rs * G[t]       + Bet[t]);
  y[t + 256] = f2b_fast(d1 * rs * G[t + 256] + Bet[t + 256]);
  y[t + 512] = f2b_fast(d2 * rs * G[t + 512] + Bet[t + 512]);
}

// ------------- LDS-staged GEMM 128x128, 4-buffer / barrier-per-2-steps --------------
// Plain __syncthreads only (compiler-managed waits). Superstep = two BK=32 steps:
// read fragments for both buffered steps, issue the two next-step stages, 32 MFMA,
// ONE barrier. WAR: stage targets buffers last read one superstep ago (covered by
// previous barrier). RAW: barrier's implicit vmcnt(0) drains the stages issued this
// superstep before they're read next superstep. Requires K % 64 == 0 (K=768 here).
// XCD swizzle + both-sides bank swizzle (chunk ^= (row>>1)&3), direct epilogue.
// modes: 0 QKV epilogue (qk/Vp), 1 bf16 C, 2 GELU bf16 C, 3 fp32 Cf (+bias)
__global__ __launch_bounds__(256)
void gemm_lds(const bf16* __restrict__ A, const bf16* __restrict__ Wt,
              const float* __restrict__ bias, bf16* __restrict__ C,
              bf16* __restrict__ Vp, float* __restrict__ Cf,
              int K, int N, int mode)
{
  __shared__ __align__(16) bf16 As[4][128 * 32];   // [buf][row][k], 64 B rows, 32 KB
  __shared__ __align__(16) bf16 Bs[4][128 * 32];   // 32 KB

  const int tid = threadIdx.x;
  const int wave = tid >> 6, lane = tid & 63;
  const int l15 = lane & 15, qd = lane >> 4;
  const int wy = wave >> 1, wx = wave & 1;

  // bijective XCD-chunked swizzle (all grids divisible by 8)
  int id = (int)blockIdx.y * (int)gridDim.x + (int)blockIdx.x;
  const int chunk = ((int)gridDim.x * (int)gridDim.y) >> 3;
  id = (id & 7) * chunk + (id >> 3);
  const int bx = id % (int)gridDim.x;
  const int by = id / (int)gridDim.x;

  const size_t m0 = (size_t)by * 128;
  const int n0 = bx * 128;

  const int r0 = tid >> 2, c0 = tid & 3;        // row 0..63, kchunk 0..3
  const int c0s = c0 ^ ((r0 >> 1) & 3);         // bank-swizzled source chunk
  const bf16* Ag0 = A  + (m0 + r0) * (size_t)K + c0s * 8;
  const bf16* Ag1 = A  + (m0 + r0 + 64) * (size_t)K + c0s * 8;
  const bf16* Bg0 = Wt + (size_t)(n0 + r0) * K + c0s * 8;
  const bf16* Bg1 = Wt + (size_t)(n0 + r0 + 64) * K + c0s * 8;

  f32x4 acc[4][4];                               // [nt][mt]
#pragma unroll
  for (int i = 0; i < 4; ++i)
#pragma unroll
    for (int j = 0; j < 4; ++j) acc[i][j] = zero4();

  const int arow = wy * 64;
  const int brow = wx * 64;
  const int ksw = (l15 >> 1) & 3;                // read-side chunk XOR

  // prologue: stage k-steps 0 and 1 into buffers 0 and 1
  load_lds16(Ag0,      &As[0][(size_t)tid * 8]);
  load_lds16(Ag1,      &As[0][(size_t)(tid + 256) * 8]);
  load_lds16(Bg0,      &Bs[0][(size_t)tid * 8]);
  load_lds16(Bg1,      &Bs[0][(size_t)(tid + 256) * 8]);
  load_lds16(Ag0 + 32, &As[1][(size_t)tid * 8]);
  load_lds16(Ag1 + 32, &As[1][(size_t)(tid + 256) * 8]);
  load_lds16(Bg0 + 32, &Bs[1][(size_t)tid * 8]);
  load_lds16(Bg1 + 32, &Bs[1][(size_t)(tid + 256) * 8]);
  __syncthreads();

  for (int k0 = 0; k0 < K; k0 += 64) {           // superstep: steps k0/32, k0/32+1
    const int s0 = (k0 >> 5) & 3;
    const int s1 = (s0 + 1) & 3;
    const bf16* A0 = &As[s0][0]; const bf16* B0 = &Bs[s0][0];
    const bf16* A1 = &As[s1][0]; const bf16* B1 = &Bs[s1][0];
    // fragment reads FIRST for BOTH steps (no vmcnt wait ahead of ds_read)
    uint4 af0[4], bf0[4], af1[4], bf1[4];
#pragma unroll
    for (int mt = 0; mt < 4; ++mt) {
      af0[mt] = *(const uint4*)(A0 + (size_t)(arow + mt * 16 + l15) * 32 + (qd ^ ksw) * 8);
      af1[mt] = *(const uint4*)(A1 + (size_t)(arow + mt * 16 + l15) * 32 + (qd ^ ksw) * 8);
    }
#pragma unroll
    for (int nt = 0; nt < 4; ++nt) {
      bf0[nt] = *(const uint4*)(B0 + (size_t)(brow + nt * 16 + l15) * 32 + (qd ^ ksw) * 8);
      bf1[nt] = *(const uint4*)(B1 + (size_t)(brow + nt * 16 + l15) * 32 + (qd ^ ksw) * 8);
    }
    if (k0 + 64 < K) {
      const int d0 = (s0 + 2) & 3;               // buffers for steps +2, +3
      const int d1 = (s1 + 2) & 3;
      load_lds16(Ag0 + k0 + 64, &As[d0][(size_t)tid * 8]);
      load_lds16(Ag1 + k0 + 64, &As[d0][(size_t)(tid + 256) * 8]);
      load_lds16(Bg0 + k0 + 64, &Bs[d0][(size_t)tid * 8]);
      load_lds16(Bg1 + k0 + 64, &Bs[d0][(size_t)(tid + 256) * 8]);
      load_lds16(Ag0 + k0 + 96, &As[d1][(size_t)tid * 8]);
      load_lds16(Ag1 + k0 + 96, &As[d1][(size_t)(tid + 256) * 8]);
      load_lds16(Bg0 + k0 + 96, &Bs[d1][(size_t)tid * 8]);
      load_lds16(Bg1 + k0 + 96, &Bs[d1][(size_t)(tid + 256) * 8]);
    }
#pragma unroll
    for (int nt = 0; nt < 4; ++nt)
#pragma unroll
      for (int mt = 0; mt < 4; ++mt)
        acc[nt][mt] = mfma16(bf0[nt], af0[mt], acc[nt][mt]);   // C^T, step A
#pragma unroll
    for (int nt = 0; nt < 4; ++nt)
#pragma unroll
      for (int mt = 0; mt < 4; ++mt)
        acc[nt][mt] = mfma16(bf1[nt], af1[mt], acc[nt][mt]);   // C^T, step B
    __syncthreads();   // drains this superstep's stages; frees s0/s1 for reuse
  }

  // epilogue: D row = out col n = brow+nt*16+qd*4+r (4 consecutive), D col = token m
  const size_t wm0 = m0 + arow;
  const int wn0 = n0 + brow;
#pragma unroll
  for (int nt = 0; nt < 4; ++nt) {
    const int nb = wn0 + nt * 16 + qd * 4;
    const f32x4 bs4 = *(const f32x4*)(bias + nb);
#pragma unroll
    for (int mt = 0; mt < 4; ++mt) {
      const size_t m = wm0 + mt * 16 + l15;
      float v[4];
#pragma unroll
      for (int r = 0; r < 4; ++r) v[r] = acc[nt][mt][r] + bs4[r];
      if (mode == 2) {
#pragma unroll
        for (int r = 0; r < 4; ++r) v[r] = fast_gelu(v[r]);
      }
      if (mode == 3) {
        f32x4 o; o.x = v[0]; o.y = v[1]; o.z = v[2]; o.w = v[3];
        *(f32x4*)(Cf + m * (size_t)N + nb) = o;
      } else if (mode == 0) {
        if (nb < SQK) {
          uint2 w; w.x = pk2bf(v[0], v[1]); w.y = pk2bf(v[2], v[3]);
          *(uint2*)(C + m * SQK + nb) = w;
        } else {
          const int bb = (int)(m >> 11);
          const int ss = (int)(m & 2047);
          const int hh = (nb - SQK) >> 6;
          const size_t vbase = (((size_t)bb * H_ + hh) * 256 + (ss >> 3)) * 512 + (ss & 7);
#pragma unroll
          for (int r = 0; r < 4; ++r)
            Vp[vbase + (size_t)((nb & 63) + r) * 8] = f2b_fast(v[r]);   // Vp[b][h][s/8][e][s&7]
        }
      } else {
        uint2 w; w.x = pk2bf(v[0], v[1]); w.y = pk2bf(v[2], v[3]);
        *(uint2*)(C + m * (size_t)N + nb) = w;
      }
    }
  }
}

// ------------- LDS-staged GEMM 128Mx64N, BK=64: for N=768 outputs (O-proj, FFN2) ----
// grid (12, M/128) = 768 blocks -> exactly 3 blocks/CU. BK=64 halves barrier count.
// 128 B LDS rows, both-sides XOR chunk swizzle (chunk ^= row&7): conflict-free.
// modes: 1 bf16 C, 3 fp32 Cf (+bias). LDS 48 KB (double-buffered) -> 3 blocks/CU.
__global__ __launch_bounds__(256)
void gemm_lds64(const bf16* __restrict__ A, const bf16* __restrict__ Wt,
                const float* __restrict__ bias, bf16* __restrict__ C,
                float* __restrict__ Cf, int K, int N, int mode)
{
  __shared__ __align__(16) bf16 As[2][128 * 64];   // 16 KB per buf
  __shared__ __align__(16) bf16 Bs[2][64 * 64];    //  8 KB per buf

  const int tid = threadIdx.x;
  const int wave = tid >> 6, lane = tid & 63;
  const int l15 = lane & 15, qd = lane >> 4;

  int id = (int)blockIdx.y * (int)gridDim.x + (int)blockIdx.x;
  const int chunk = ((int)gridDim.x * (int)gridDim.y) >> 3;
  id = (id & 7) * chunk + (id >> 3);
  const int bx = id % (int)gridDim.x;
  const int by = id / (int)gridDim.x;

  const size_t m0 = (size_t)by * 128;
  const int n0 = bx * 64;

  // staging: row = tid>>3 (0..31, +32/pass), chunk = tid&7; source chunk pre-swizzled
  const int srow = tid >> 3;
  const int sch  = (tid & 7) ^ (srow & 7);
  const bf16* Ag = A  + (m0 + srow) * (size_t)K + sch * 8;
  const bf16* Bg = Wt + (size_t)(n0 + srow) * K + sch * 8;

  f32x4 acc[4][2];                               // [nt][mt]
#pragma unroll
  for (int i = 0; i < 4; ++i)
#pragma unroll
    for (int j = 0; j < 2; ++j) acc[i][j] = zero4();

  const int arow = wave * 32;
  const int ksw = l15 & 7;                       // read-side chunk XOR

  // prologue: stage k-tile 0 into buffer 0 (A: 4 passes, B: 2 passes)
#pragma unroll
  for (int p = 0; p < 4; ++p)
    load_lds16(Ag + (size_t)32 * p * K, &As[0][(size_t)(tid + 256 * p) * 8]);
#pragma unroll
  for (int p = 0; p < 2; ++p)
    load_lds16(Bg + (size_t)32 * p * K, &Bs[0][(size_t)(tid + 256 * p) * 8]);
  __syncthreads();

  for (int k0 = 0; k0 < K; k0 += 64) {
    const int cur = (k0 >> 6) & 1;
    // fragment reads FIRST
    uint4 af[2][2], bfr[4][2];
#pragma unroll
    for (int mt = 0; mt < 2; ++mt)
#pragma unroll
      for (int ks = 0; ks < 2; ++ks)
        af[mt][ks] = *(const uint4*)(&As[cur][0]
                       + (size_t)(arow + mt * 16 + l15) * 64 + ((ks * 4 + qd) ^ ksw) * 8);
#pragma unroll
    for (int nt = 0; nt < 4; ++nt)
#pragma unroll
      for (int ks = 0; ks < 2; ++ks)
        bfr[nt][ks] = *(const uint4*)(&Bs[cur][0]
                       + (size_t)(nt * 16 + l15) * 64 + ((ks * 4 + qd) ^ ksw) * 8);
    if (k0 + 64 < K) {
      const int nxt = cur ^ 1;
#pragma unroll
      for (int p = 0; p < 4; ++p)
        load_lds16(Ag + (size_t)32 * p * K + k0 + 64, &As[nxt][(size_t)(tid + 256 * p) * 8]);
#pragma unroll
      for (int p = 0; p < 2; ++p)
        load_lds16(Bg + (size_t)32 * p * K + k0 + 64, &Bs[nxt][(size_t)(tid + 256 * p) * 8]);
    }
#pragma unroll
    for (int ks = 0; ks < 2; ++ks)
#pragma unroll
      for (int nt = 0; nt < 4; ++nt)
#pragma unroll
        for (int mt = 0; mt < 2; ++mt)
          acc[nt][mt] = mfma16(bfr[nt][ks], af[mt][ks], acc[nt][mt]);   // C^T
    __syncthreads();
  }

  const size_t wm0 = m0 + arow;
#pragma unroll
  for (int nt = 0; nt < 4; ++nt) {
    const int nb = n0 + nt * 16 + qd * 4;
    const f32x4 bs4 = *(const f32x4*)(bias + nb);
#pragma unroll
    for (int mt = 0; mt < 2; ++mt) {
      const size_t m = wm0 + mt * 16 + l15;
      float v[4];
#pragma unroll
      for (int r = 0; r < 4; ++r) v[r] = acc[nt][mt][r] + bs4[r];
      if (mode == 3) {
        f32x4 o; o.x = v[0]; o.y = v[1]; o.z = v[2]; o.w = v[3];
        *(f32x4*)(Cf + m * (size_t)N + nb) = o;
      } else {
        uint2 w; w.x = pk2bf(v[0], v[1]); w.y = pk2bf(v[2], v[3]);
        *(uint2*)(C + m * (size_t)N + nb) = w;
      }
    }
  }
}

// ---------------- flash attention v2: block = 128 q-rows of one (b,h), 4 waves -------
__global__ __launch_bounds__(256, 3)
void attn_kernel(const bf16* __restrict__ QK, const bf16* __restrict__ Vp,
                 bf16* __restrict__ O)
{
  const int tid  = threadIdx.x;
  const int wave = tid >> 6;
  const int lane = tid & 63;
  const int l15 = lane & 15;
  const int qd  = lane >> 4;

  // bijective XCD-chunked block swizzle: 768 blocks, 8 XCDs, 96 blocks/XCD
  int bid = blockIdx.y * gridDim.x + blockIdx.x;
  bid = (bid & 7) * 96 + (bid >> 3);
  const int bh = bid >> 4;                       // 0..47
  const int b  = bh / H_;
  const int h  = bh % H_;
  const int q0 = (bid & 15) * 128 + wave * 32;   // this wave's first q-row

  const bf16* Qb = QK + (size_t)b * S_ * SQK + h * HD_;
  const bf16* Kb = Qb + D_;                       // K block lives at col+768
  const bf16* Vb = Vp + (size_t)bh * 256 * 512;

  __shared__ __align__(16) bf16 Ks[2][64 * 64];             // 8 KB x2, chunk ^= row&7
  __shared__ __align__(16) bf16 Vs[2][8 * 512];             // 8 KB x2, packed V tile
  __shared__ __align__(16) unsigned short Pl[4][32 * PSTR]; // 18 KB, per-wave private
  unsigned short* Pw = &Pl[wave][0];

  // staging coords: per 256-thread pass, row = tid>>3 (0..31), chunk = tid&7
  const int srow = tid >> 3;
  const int sch  = (tid & 7) ^ (srow & 7);       // pre-swizzled source chunk
  const bf16* Kst = Kb + (size_t)srow * SQK + sch * 8;
  const bf16* Vst = Vb + tid * 8;

  uint4 qf[2][2];
#pragma unroll
  for (int mt = 0; mt < 2; ++mt)
#pragma unroll
    for (int ks = 0; ks < 2; ++ks)
      qf[mt][ks] = *(const uint4*)(Qb + (size_t)(q0 + mt * 16 + l15) * SQK + ks * 32 + qd * 8);

  f32x4 o_[2][5];                               // [..][4] = ones-column row-sums (l)
#pragma unroll
  for (int mt = 0; mt < 2; ++mt)
#pragma unroll
    for (int dt = 0; dt < 5; ++dt) o_[mt][dt] = zero4();

  // constant ones-column B fragment: B[k][n] = (n==0) ? 1 : 0
  uint4 vones;
  { const unsigned v = (l15 == 0) ? 0x3F803F80u : 0u; vones.x = v; vones.y = v; vones.z = v; vones.w = v; }

  const float C1 = 1.4426950408889634f * 0.125f;   // log2e / 8
  const float C0 = -12.0f * 1.4426950408889634f;   // -M0 * log2e

  // prologue: stage tile 0 into buffer 0
  load_lds16(Kst,                      &Ks[0][tid * 8]);
  load_lds16(Kst + (size_t)32 * SQK,   &Ks[0][2048 + tid * 8]);
  load_lds16(Vst,                      &Vs[0][tid * 8]);
  load_lds16(Vst + 2048,               &Vs[0][2048 + tid * 8]);
  __syncthreads();                                 // drains vmcnt(0)

  for (int sk = 0; sk < S_; sk += 64) {
    const int cur = (sk >> 6) & 1;
    const bf16* Ksc = &Ks[cur][0];
    const bf16* Vsc = &Vs[cur][0];

    // --- LDS reads FIRST ---
    uint4 kf[4][2];
#pragma unroll
    for (int kt = 0; kt < 4; ++kt)
#pragma unroll
      for (int ks = 0; ks < 2; ++ks)
        kf[kt][ks] = *(const uint4*)(Ksc + (size_t)(kt * 16 + l15) * 64
                                         + ((ks * 4 + qd) ^ (l15 & 7)) * 8);
    uint4 vf[2][4];
#pragma unroll
    for (int ks = 0; ks < 2; ++ks)
#pragma unroll
      for (int dt = 0; dt < 4; ++dt)
        vf[ks][dt] = *(const uint4*)(Vsc + (ks * 4 + qd) * 512 + (dt * 16 + l15) * 8);

    // --- async-stage next tile; latency hidden under this step's compute ---
    if (sk + 64 < S_) {
      const int nxt = cur ^ 1;
      const bf16* Kn = Kst + (size_t)(sk + 64) * SQK;
      const bf16* Vn = Vst + (size_t)(sk + 64) * 64;
      load_lds16(Kn,                    &Ks[nxt][tid * 8]);
      load_lds16(Kn + (size_t)32 * SQK, &Ks[nxt][2048 + tid * 8]);
      load_lds16(Vn,                    &Vs[nxt][tid * 8]);
      load_lds16(Vn + 2048,             &Vs[nxt][2048 + tid * 8]);
    }

    // --- S^T[key][q] = K·Q^T ---
    f32x4 st[4][2];
#pragma unroll
    for (int kt = 0; kt < 4; ++kt)
#pragma unroll
      for (int mt = 0; mt < 2; ++mt) st[kt][mt] = zero4();
    __builtin_amdgcn_s_setprio(1);
#pragma unroll
    for (int ks = 0; ks < 2; ++ks)
#pragma unroll
      for (int kt = 0; kt < 4; ++kt)
#pragma unroll
        for (int mt = 0; mt < 2; ++mt)
          st[kt][mt] = mfma16(kf[kt][ks], qf[mt][ks], st[kt][mt]);
    __builtin_amdgcn_s_setprio(0);

    // --- p = exp2(fma(s,C1,C0)); 4 consecutive keys/lane -> one b64 LDS write ---
#pragma unroll
    for (int mt = 0; mt < 2; ++mt) {
      unsigned short* prow = Pw + (mt * 16 + l15) * PSTR;
#pragma unroll
      for (int kt = 0; kt < 4; ++kt) {
        const float p0 = __builtin_amdgcn_exp2f(fmaf(st[kt][mt][0], C1, C0));
        const float p1 = __builtin_amdgcn_exp2f(fmaf(st[kt][mt][1], C1, C0));
        const float p2 = __builtin_amdgcn_exp2f(fmaf(st[kt][mt][2], C1, C0));
        const float p3 = __builtin_amdgcn_exp2f(fmaf(st[kt][mt][3], C1, C0));
        uint2 w; w.x = pk2bf(p0, p1); w.y = pk2bf(p2, p3);
        *(uint2*)(prow + kt * 16 + qd * 4) = w;
      }
    }

    // --- read P as A-fragments (same wave; DS in-order) ---
    uint4 pf[2][2];
#pragma unroll
    for (int mt = 0; mt < 2; ++mt)
#pragma unroll
      for (int ks = 0; ks < 2; ++ks)
        pf[mt][ks] = *(const uint4*)(Pw + (mt * 16 + l15) * PSTR + ks * 32 + qd * 8);

    // --- O += P V ; l += P * ones ---
    __builtin_amdgcn_s_setprio(1);
#pragma unroll
    for (int ks = 0; ks < 2; ++ks)
#pragma unroll
      for (int mt = 0; mt < 2; ++mt) {
#pragma unroll
        for (int dt = 0; dt < 4; ++dt)
          o_[mt][dt] = mfma16(pf[mt][ks], vf[ks][dt], o_[mt][dt]);
        o_[mt][4] = mfma16(pf[mt][ks], vones, o_[mt][4]);
      }
    __builtin_amdgcn_s_setprio(0);

    // barrier: all waves done reading buf[cur]; stage for buf[nxt] drained here
    __syncthreads();
  }

  // --- epilogue: O / l  -> o_buf[b, s, h*64 + e]; l lives on l15==0 lanes ---
  const size_t tok0 = (size_t)b * S_ + q0;
#pragma unroll
  for (int mt = 0; mt < 2; ++mt) {
#pragma unroll
    for (int r = 0; r < 4; ++r) {
      const float lr = __shfl(o_[mt][4][r], (lane & 48), 64);
      const float inv = __builtin_amdgcn_rcpf(lr);
      const size_t row = tok0 + mt * 16 + qd * 4 + r;
#pragma unroll
      for (int dt = 0; dt < 4; ++dt)
        O[row * D_ + h * HD_ + dt * 16 + l15] = f2b_fast(o_[mt][dt][r] * inv);
    }
  }
}

// ---------------- orchestration ----------------
extern "C" void kernel_launch(void* const* d_in, const int* in_sizes, int n_in,
                              void* d_out, int out_size, void* d_ws, size_t ws_size,
                              hipStream_t stream)
{
  const float* x   = (const float*)d_in[0];
  const float* Wq  = (const float*)d_in[1];
  const float* bq  = (const float*)d_in[2];
  const float* Wk  = (const float*)d_in[3];
  const float* bk  = (const float*)d_in[4];
  const float* Wv  = (const float*)d_in[5];
  const float* bv  = (const float*)d_in[6];
  const float* Wo  = (const float*)d_in[7];
  const float* bo  = (const float*)d_in[8];
  const float* W1  = (const float*)d_in[9];
  const float* b1  = (const float*)d_in[10];
  const float* W2  = (const float*)d_in[11];
  const float* b2  = (const float*)d_in[12];
  const float* g1  = (const float*)d_in[13];
  const float* be1 = (const float*)d_in[14];
  const float* g2  = (const float*)d_in[15];
  const float* be2 = (const float*)d_in[16];

  // full-M FFN needs 77,079,552 B of workspace; otherwise split (64,496,640 B)
  const bool full = ws_size >= (size_t)77079552;

  char* ws = (char*)d_ws;
  bf16* qk     = (bf16*)(ws + 0);           // QKV gemm -> attn
  bf16* vp     = (bf16*)(ws + 25165824);    // QKV gemm -> attn
  bf16* h1     = (bf16*)(ws + 37748736);    // LN1 -> QKV gemm
  bf16* obuf   = h1;                        // attn -> O-proj (h1 dead)
  bf16* abuf   = (bf16*)(ws + 0);           // O-proj -> LN2 (qk dead)
  bf16* h2     = (bf16*)(ws + (full ? 50331648u : 25165824u));  // LN2 -> FFN1
  bf16* fbuf   = (bf16*)(ws + 0);           // FFN1 -> FFN2 (full: 48 MB; split: 24 MB)
  const size_t wb = full ? 62914560u : 50331648u;
  bf16* wqkv_p = (bf16*)(ws + wb);                    // 3,538,944 B
  bf16* wo_p   = (bf16*)(ws + wb + 3538944u);         // 1,179,648 B
  bf16* w1_p   = (bf16*)(ws + wb + 4718592u);         // 4,718,592 B
  bf16* w2_p   = (bf16*)(ws + wb + 9437184u);         // 4,718,592 B
  float* bqkvf = (float*)(ws + wb + 14155776u);       // 9,216 B

  float* outp = (float*)d_out;

  repack_qkv_t<<<dim3(864),  dim3(256), 0, stream>>>(Wq, Wk, Wv, wqkv_p);
  repack_t    <<<dim3(288),  dim3(256), 0, stream>>>(Wo, wo_p, 768, 768);
  repack_t    <<<dim3(1152), dim3(256), 0, stream>>>(W1, w1_p, 768, 3072);
  repack_t    <<<dim3(1152), dim3(256), 0, stream>>>(W2, w2_p, 3072, 768);
  bias_qkv    <<<dim3(9),    dim3(256), 0, stream>>>(bq, bk, bv, bqkvf);

  ln_x_kernel<<<dim3(BS_), dim3(256), 0, stream>>>(x, g1, be1, h1);
  gemm_lds<<<dim3(18, 64), dim3(256), 0, stream>>>(h1, wqkv_p, bqkvf, qk, vp, nullptr, 768, 2304, 0);
  attn_kernel<<<dim3(16, 48), dim3(256), 0, stream>>>(qk, vp, obuf);
  gemm_lds64<<<dim3(12, 64), dim3(256), 0, stream>>>(obuf, wo_p, bo, abuf, nullptr, 768, 768, 1);
  ln_h_kernel<<<dim3(BS_), dim3(256), 0, stream>>>(abuf, g2, be2, h2);

  if (full) {
    gemm_lds<<<dim3(24, 64), dim3(256), 0, stream>>>(h2, w1_p, b1, fbuf, nullptr, nullptr, 768, 3072, 2);
    gemm_lds64<<<dim3(12, 64), dim3(256), 0, stream>>>(fbuf, w2_p, b2, nullptr, outp, 3072, 768, 3);
  } else {
    gemm_lds<<<dim3(24, 32), dim3(256), 0, stream>>>(h2, w1_p, b1, fbuf, nullptr, nullptr, 768, 3072, 2);
    gemm_lds64<<<dim3(12, 32), dim3(256), 0, stream>>>(fbuf, w2_p, b2, nullptr, outp, 3072, 768, 3);
    gemm_lds<<<dim3(24, 32), dim3(256), 0, stream>>>(h2 + (size_t)4096 * D_, w1_p, b1, fbuf, nullptr, nullptr, 768, 3072, 2);
    gemm_lds64<<<dim3(12, 32), dim3(256), 0, stream>>>(fbuf, w2_p, b2, nullptr, outp + (size_t)4096 * D_, 3072, 768, 3);
  }
}

// Round 12
// 378.606 us; speedup vs baseline: 1.0592x; 1.0592x over previous
//
#include <hip/hip_runtime.h>
#include <hip/hip_bf16.h>
#include <math.h>

typedef __hip_bfloat16 bf16;
typedef __attribute__((ext_vector_type(8))) short short8;
typedef __attribute__((ext_vector_type(4))) float f32x4;

#define D_  768
#define H_  12
#define HD_ 64
#define F_  3072
#define B_  4
#define S_  2048
#define BS_ (B_*S_)
#define SQK 1536   // Q,K buffer row stride (V lives in packed Vp)
#define PSTR 72    // P LDS row stride in u16 (64 + 8 pad; 144 B = 16B-aligned rows)

__device__ __forceinline__ float b2f(bf16 x){ return __bfloat162float(x); }

union BU { bf16 b; unsigned short u; };
// fast bf16 round (half-away ties; inputs are finite, non-NaN)
__device__ __forceinline__ bf16 f2b_fast(float x){
  BU t; t.u = (unsigned short)((__float_as_uint(x) + 0x8000u) >> 16); return t.b;
}
// pack two floats -> bf16x2 dword (low u16 = a)
__device__ __forceinline__ unsigned pk2bf(float a, float b){
  return __builtin_amdgcn_perm(__float_as_uint(b) + 0x8000u,
                               __float_as_uint(a) + 0x8000u, 0x07060302u);
}

__device__ __forceinline__ f32x4 zero4(){ f32x4 z; z.x=0.f; z.y=0.f; z.z=0.f; z.w=0.f; return z; }

__device__ __forceinline__ f32x4 mfma16(uint4 a, uint4 b, f32x4 c){
  union U { uint4 u; short8 s; };
  U A, B; A.u = a; B.u = b;
  return __builtin_amdgcn_mfma_f32_16x16x32_bf16(A.s, B.s, c, 0, 0, 0);
}

// async global->LDS, 16 B per lane (global_load_lds_dwordx4)
typedef const __attribute__((address_space(1))) void gvoid;
typedef __attribute__((address_space(3))) void lvoid;
__device__ __forceinline__ void load_lds16(const void* g, void* l){
  __builtin_amdgcn_global_load_lds((gvoid*)g, (lvoid*)l, 16, 0, 0);
}

// exact-accuracy GELU via A&S 7.1.26 erf (|eps| <= 1.5e-7), HW exp/rcp
__device__ __forceinline__ float fast_gelu(float v){
  const float x = v * 0.70710678118654752f;
  const float ax = fabsf(x);
  const float t = __builtin_amdgcn_rcpf(fmaf(0.3275911f, ax, 1.0f));
  const float poly = t * fmaf(t, fmaf(t, fmaf(t, fmaf(t, 1.061405429f, -1.453152027f),
                                              1.421413741f), -0.284496736f), 0.254829592f);
  const float e = __builtin_amdgcn_exp2f(ax * ax * -1.4426950408889634f);
  const float erfax = 1.0f - poly * e;
  const float erfx = copysignf(erfax, x);
  return 0.5f * v * (1.0f + erfx);
}

// ------------- weight repack body (fp32 -> bf16 W^T): Wt[n][k] = W[k][n] -----------
__device__ __forceinline__ void repack_body(const float* __restrict__ W,
                                            bf16* __restrict__ Wt, int K, int N, int t)
{
  const int n = t % N;
  const int kg = t / N;
  const float* src = W + (size_t)kg * 8 * N + n;
  union { unsigned u32[4]; uint4 u; } pk;
#pragma unroll
  for (int j = 0; j < 4; ++j)
    pk.u32[j] = pk2bf(src[(size_t)(2 * j) * N], src[(size_t)(2 * j + 1) * N]);
  *(uint4*)(Wt + ((size_t)n * (K >> 3) + kg) * 8) = pk.u;
}

// ------------- single prep kernel: all weight repacks + bias concat ----------------
// blocks [0,864): QKV combined W^T; [864,1152): Wo; [1152,2304): W1; [2304,3456): W2;
// [3456,3465): bias concat. Per-branch bodies are byte-exact ports of the previous
// standalone kernels (indexing proven in R1-R10).
__global__ __launch_bounds__(256)
void repack_all(const float* __restrict__ Wq, const float* __restrict__ Wk,
                const float* __restrict__ Wv, const float* __restrict__ Wo,
                const float* __restrict__ W1, const float* __restrict__ W2,
                const float* __restrict__ bq, const float* __restrict__ bk,
                const float* __restrict__ bv,
                bf16* __restrict__ wqkv_p, bf16* __restrict__ wo_p,
                bf16* __restrict__ w1_p, bf16* __restrict__ w2_p,
                float* __restrict__ bqkvf)
{
  const int bid = blockIdx.x;
  if (bid < 864) {
    // QKV combined W^T: rows n in [0,2304): sel=n/768, h=(n%768)>>6, e=n&63; K=768
    const int t = bid * 256 + threadIdx.x;        // 864*256 = 96*2304 exact
    const int n = t % 2304;
    const int kg = t / 2304;                      // 0..95
    const int sel = n / 768;
    const int nn = n - sel * 768;
    const int hh = nn >> 6;
    const int ee = nn & 63;
    const float* W = (sel == 0) ? Wq : (sel == 1) ? Wk : Wv;
    const float* src = W + ((size_t)hh * 768 + (size_t)kg * 8) * 64 + ee;
    union { unsigned u32[4]; uint4 u; } pk;
#pragma unroll
    for (int j = 0; j < 4; ++j)
      pk.u32[j] = pk2bf(src[(size_t)(2 * j) * 64], src[(size_t)(2 * j + 1) * 64]);
    *(uint4*)(wqkv_p + ((size_t)n * 96 + kg) * 8) = pk.u;
  } else if (bid < 1152) {
    repack_body(Wo, wo_p, 768, 768, (bid - 864) * 256 + threadIdx.x);
  } else if (bid < 2304) {
    repack_body(W1, w1_p, 768, 3072, (bid - 1152) * 256 + threadIdx.x);
  } else if (bid < 3456) {
    repack_body(W2, w2_p, 3072, 768, (bid - 2304) * 256 + threadIdx.x);
  } else {
    const int t = (bid - 3456) * 256 + threadIdx.x;   // 9*256 = 2304 exact
    bqkvf[t] = (t < 768) ? bq[t] : (t < 1536) ? bk[t - 768] : bv[t - 1536];
  }
}

// ---------------- LayerNorm: one block per token, 256 thr, D=768=256*3 ----------------
__global__ __launch_bounds__(256)
void ln_x_kernel(const float* __restrict__ X, const float* __restrict__ G,
                 const float* __restrict__ Bet, bf16* __restrict__ Y)
{
  const int t = threadIdx.x;
  const size_t row = blockIdx.x;
  const float* x = X + row * D_;
  float v0 = x[t], v1 = x[t + 256], v2 = x[t + 512];
  float s = v0 + v1 + v2;
#pragma unroll
  for (int d = 32; d >= 1; d >>= 1) s += __shfl_xor(s, d, 64);
  __shared__ float red[8];
  const int wv = t >> 6, ln = t & 63;
  if (ln == 0) red[wv] = s;
  __syncthreads();
  const float mu = (red[0] + red[1] + red[2] + red[3]) * (1.0f / 768.0f);
  const float d0 = v0 - mu, d1 = v1 - mu, d2 = v2 - mu;
  float sq = d0 * d0 + d1 * d1 + d2 * d2;
#pragma unroll
  for (int d = 32; d >= 1; d >>= 1) sq += __shfl_xor(sq, d, 64);
  if (ln == 0) red[4 + wv] = sq;
  __syncthreads();
  const float var = (red[4] + red[5] + red[6] + red[7]) * (1.0f / 768.0f);
  const float rs = rsqrtf(var + 1e-5f);
  bf16* y = Y + row * D_;
  y[t]       = f2b_fast(d0 * rs * G[t]       + Bet[t]);
  y[t + 256] = f2b_fast(d1 * rs * G[t + 256] + Bet[t + 256]);
  y[t + 512] = f2b_fast(d2 * rs * G[t + 512] + Bet[t + 512]);
}

// LN over bf16 input:
__global__ __launch_bounds__(256)
void ln_h_kernel(const bf16* __restrict__ X, const float* __restrict__ G,
                 const float* __restrict__ Bet, bf16* __restrict__ Y)
{
  const int t = threadIdx.x;
  const size_t row = blockIdx.x;
  const bf16* x = X + row * D_;
  float v0 = b2f(x[t]), v1 = b2f(x[t + 256]), v2 = b2f(x[t + 512]);
  float s = v0 + v1 + v2;
#pragma unroll
  for (int d = 32; d >= 1; d >>= 1) s += __shfl_xor(s, d, 64);
  __shared__ float red[8];
  const int wv = t >> 6, ln = t & 63;
  if (ln == 0) red[wv] = s;
  __syncthreads();
  const float mu = (red[0] + red[1] + red[2] + red[3]) * (1.0f / 768.0f);
  const float d0 = v0 - mu, d1 = v1 - mu, d2 = v2 - mu;
  float sq = d0 * d0 + d1 * d1 + d2 * d2;
#pragma unroll
  for (int d = 32; d >= 1; d >>= 1) sq += __shfl_xor(sq, d, 64);
  if (ln == 0) red[4 + wv] = sq;
  __syncthreads();
  const float var = (red[4] + red[5] + red[6] + red[7]) * (1.0f / 768.0f);
  const float rs = rsqrtf(var + 1e-5f);
  bf16* y = Y + row * D_;
  y[t]       = f2b_fast(d0 * rs * G[t]       + Bet[t]);
  y[t + 256] = f2b_fast(d1 * rs * G[t + 256] + Bet[t + 256]);
  y[t + 512] = f2b_fast(d2 * rs * G[t + 512] + Bet[t + 512]);
}

// ------------- LDS-staged GEMM 128x128 (R4-exact): double-buffered prefetch,
// XCD swizzle, both-sides bank swizzle (chunk ^= (row>>1)&3), ds_reads-first,
// direct epilogue. modes: 0 QKV epilogue (qk/Vp), 1 bf16 C, 2 GELU bf16 C,
// 3 fp32 Cf (+bias)
__global__ __launch_bounds__(256)
void gemm_lds(const bf16* __restrict__ A, const bf16* __restrict__ Wt,
              const float* __restrict__ bias, bf16* __restrict__ C,
              bf16* __restrict__ Vp, float* __restrict__ Cf,
              int K, int N, int mode)
{
  __shared__ __align__(16) bf16 As[2][128 * 32];   // [buf][row][k], 64 B rows
  __shared__ __align__(16) bf16 Bs[2][128 * 32];

  const int tid = threadIdx.x;
  const int wave = tid >> 6, lane = tid & 63;
  const int l15 = lane & 15, qd = lane >> 4;
  const int wy = wave >> 1, wx = wave & 1;

  // bijective XCD-chunked swizzle (all grids divisible by 8)
  int id = (int)blockIdx.y * (int)gridDim.x + (int)blockIdx.x;
  const int chunk = ((int)gridDim.x * (int)gridDim.y) >> 3;
  id = (id & 7) * chunk + (id >> 3);
  const int bx = id % (int)gridDim.x;
  const int by = id / (int)gridDim.x;

  const size_t m0 = (size_t)by * 128;
  const int n0 = bx * 128;

  const int r0 = tid >> 2, c0 = tid & 3;        // row 0..63, kchunk 0..3
  const int c0s = c0 ^ ((r0 >> 1) & 3);         // bank-swizzled source chunk
  const bf16* Ag0 = A  + (m0 + r0) * (size_t)K + c0s * 8;
  const bf16* Ag1 = A  + (m0 + r0 + 64) * (size_t)K + c0s * 8;
  const bf16* Bg0 = Wt + (size_t)(n0 + r0) * K + c0s * 8;
  const bf16* Bg1 = Wt + (size_t)(n0 + r0 + 64) * K + c0s * 8;

  f32x4 acc[4][4];                               // [nt][mt]
#pragma unroll
  for (int i = 0; i < 4; ++i)
#pragma unroll
    for (int j = 0; j < 4; ++j) acc[i][j] = zero4();

  const int arow = wy * 64;
  const int brow = wx * 64;
  const int ksw = (l15 >> 1) & 3;                // read-side chunk XOR

  // prologue: stage k-tile 0 into buffer 0
  load_lds16(Ag0, &As[0][(size_t)tid * 8]);
  load_lds16(Ag1, &As[0][(size_t)(tid + 256) * 8]);
  load_lds16(Bg0, &Bs[0][(size_t)tid * 8]);
  load_lds16(Bg1, &Bs[0][(size_t)(tid + 256) * 8]);
  __syncthreads();

  for (int k0 = 0; k0 < K; k0 += 32) {
    const int cur = (k0 >> 5) & 1;
    // fragment reads FIRST (alias ordering: no vmcnt wait ahead of ds_read)
    uint4 af[4], bfr[4];
#pragma unroll
    for (int mt = 0; mt < 4; ++mt)
      af[mt] = *(const uint4*)(&As[cur][0] + (size_t)(arow + mt * 16 + l15) * 32 + (qd ^ ksw) * 8);
#pragma unroll
    for (int nt = 0; nt < 4; ++nt)
      bfr[nt] = *(const uint4*)(&Bs[cur][0] + (size_t)(brow + nt * 16 + l15) * 32 + (qd ^ ksw) * 8);
    if (k0 + 32 < K) {
      const int nxt = cur ^ 1;
      load_lds16(Ag0 + k0 + 32, &As[nxt][(size_t)tid * 8]);
      load_lds16(Ag1 + k0 + 32, &As[nxt][(size_t)(tid + 256) * 8]);
      load_lds16(Bg0 + k0 + 32, &Bs[nxt][(size_t)tid * 8]);
      load_lds16(Bg1 + k0 + 32, &Bs[nxt][(size_t)(tid + 256) * 8]);
    }
#pragma unroll
    for (int nt = 0; nt < 4; ++nt)
#pragma unroll
      for (int mt = 0; mt < 4; ++mt)
        acc[nt][mt] = mfma16(bfr[nt], af[mt], acc[nt][mt]);   // C^T
    __syncthreads();   // drains prefetch vmcnt + all waves done reading buf[cur]
  }

  // epilogue: D row = out col n = brow+nt*16+qd*4+r (4 consecutive), D col = token m
  const size_t wm0 = m0 + arow;
  const int wn0 = n0 + brow;
#pragma unroll
  for (int nt = 0; nt < 4; ++nt) {
    const int nb = wn0 + nt * 16 + qd * 4;
    const f32x4 bs4 = *(const f32x4*)(bias + nb);
#pragma unroll
    for (int mt = 0; mt < 4; ++mt) {
      const size_t m = wm0 + mt * 16 + l15;
      float v[4];
#pragma unroll
      for (int r = 0; r < 4; ++r) v[r] = acc[nt][mt][r] + bs4[r];
      if (mode == 2) {
#pragma unroll
        for (int r = 0; r < 4; ++r) v[r] = fast_gelu(v[r]);
      }
      if (mode == 3) {
        f32x4 o; o.x = v[0]; o.y = v[1]; o.z = v[2]; o.w = v[3];
        *(f32x4*)(Cf + m * (size_t)N + nb) = o;
      } else if (mode == 0) {
        if (nb < SQK) {
          uint2 w; w.x = pk2bf(v[0], v[1]); w.y = pk2bf(v[2], v[3]);
          *(uint2*)(C + m * SQK + nb) = w;
        } else {
          const int bb = (int)(m >> 11);
          const int ss = (int)(m & 2047);
          const int hh = (nb - SQK) >> 6;
          const size_t vbase = (((size_t)bb * H_ + hh) * 256 + (ss >> 3)) * 512 + (ss & 7);
#pragma unroll
          for (int r = 0; r < 4; ++r)
            Vp[vbase + (size_t)((nb & 63) + r) * 8] = f2b_fast(v[r]);   // Vp[b][h][s/8][e][s&7]
        }
      } else {
        uint2 w; w.x = pk2bf(v[0], v[1]); w.y = pk2bf(v[2], v[3]);
        *(uint2*)(C + m * (size_t)N + nb) = w;
      }
    }
  }
}

// ------------- LDS-staged GEMM 128Mx64N, BK=64: for N=768 outputs (O-proj, FFN2) ----
// grid (12, M/128) = 768 blocks -> exactly 3 blocks/CU. BK=64 halves barrier count.
// 128 B LDS rows, both-sides XOR chunk swizzle (chunk ^= row&7): conflict-free.
// modes: 1 bf16 C, 3 fp32 Cf (+bias). LDS 48 KB (double-buffered) -> 3 blocks/CU.
__global__ __launch_bounds__(256)
void gemm_lds64(const bf16* __restrict__ A, const bf16* __restrict__ Wt,
                const float* __restrict__ bias, bf16* __restrict__ C,
                float* __restrict__ Cf, int K, int N, int mode)
{
  __shared__ __align__(16) bf16 As[2][128 * 64];   // 16 KB per buf
  __shared__ __align__(16) bf16 Bs[2][64 * 64];    //  8 KB per buf

  const int tid = threadIdx.x;
  const int wave = tid >> 6, lane = tid & 63;
  const int l15 = lane & 15, qd = lane >> 4;

  int id = (int)blockIdx.y * (int)gridDim.x + (int)blockIdx.x;
  const int chunk = ((int)gridDim.x * (int)gridDim.y) >> 3;
  id = (id & 7) * chunk + (id >> 3);
  const int bx = id % (int)gridDim.x;
  const int by = id / (int)gridDim.x;

  const size_t m0 = (size_t)by * 128;
  const int n0 = bx * 64;

  // staging: row = tid>>3 (0..31, +32/pass), chunk = tid&7; source chunk pre-swizzled
  const int srow = tid >> 3;
  const int sch  = (tid & 7) ^ (srow & 7);
  const bf16* Ag = A  + (m0 + srow) * (size_t)K + sch * 8;
  const bf16* Bg = Wt + (size_t)(n0 + srow) * K + sch * 8;

  f32x4 acc[4][2];                               // [nt][mt]
#pragma unroll
  for (int i = 0; i < 4; ++i)
#pragma unroll
    for (int j = 0; j < 2; ++j) acc[i][j] = zero4();

  const int arow = wave * 32;
  const int ksw = l15 & 7;                       // read-side chunk XOR

  // prologue: stage k-tile 0 into buffer 0 (A: 4 passes, B: 2 passes)
#pragma unroll
  for (int p = 0; p < 4; ++p)
    load_lds16(Ag + (size_t)32 * p * K, &As[0][(size_t)(tid + 256 * p) * 8]);
#pragma unroll
  for (int p = 0; p < 2; ++p)
    load_lds16(Bg + (size_t)32 * p * K, &Bs[0][(size_t)(tid + 256 * p) * 8]);
  __syncthreads();

  for (int k0 = 0; k0 < K; k0 += 64) {
    const int cur = (k0 >> 6) & 1;
    // fragment reads FIRST
    uint4 af[2][2], bfr[4][2];
#pragma unroll
    for (int mt = 0; mt < 2; ++mt)
#pragma unroll
      for (int ks = 0; ks < 2; ++ks)
        af[mt][ks] = *(const uint4*)(&As[cur][0]
                       + (size_t)(arow + mt * 16 + l15) * 64 + ((ks * 4 + qd) ^ ksw) * 8);
#pragma unroll
    for (int nt = 0; nt < 4; ++nt)
#pragma unroll
      for (int ks = 0; ks < 2; ++ks)
        bfr[nt][ks] = *(const uint4*)(&Bs[cur][0]
                       + (size_t)(nt * 16 + l15) * 64 + ((ks * 4 + qd) ^ ksw) * 8);
    if (k0 + 64 < K) {
      const int nxt = cur ^ 1;
#pragma unroll
      for (int p = 0; p < 4; ++p)
        load_lds16(Ag + (size_t)32 * p * K + k0 + 64, &As[nxt][(size_t)(tid + 256 * p) * 8]);
#pragma unroll
      for (int p = 0; p < 2; ++p)
        load_lds16(Bg + (size_t)32 * p * K + k0 + 64, &Bs[nxt][(size_t)(tid + 256 * p) * 8]);
    }
#pragma unroll
    for (int ks = 0; ks < 2; ++ks)
#pragma unroll
      for (int nt = 0; nt < 4; ++nt)
#pragma unroll
        for (int mt = 0; mt < 2; ++mt)
          acc[nt][mt] = mfma16(bfr[nt][ks], af[mt][ks], acc[nt][mt]);   // C^T
    __syncthreads();
  }

  const size_t wm0 = m0 + arow;
#pragma unroll
  for (int nt = 0; nt < 4; ++nt) {
    const int nb = n0 + nt * 16 + qd * 4;
    const f32x4 bs4 = *(const f32x4*)(bias + nb);
#pragma unroll
    for (int mt = 0; mt < 2; ++mt) {
      const size_t m = wm0 + mt * 16 + l15;
      float v[4];
#pragma unroll
      for (int r = 0; r < 4; ++r) v[r] = acc[nt][mt][r] + bs4[r];
      if (mode == 3) {
        f32x4 o; o.x = v[0]; o.y = v[1]; o.z = v[2]; o.w = v[3];
        *(f32x4*)(Cf + m * (size_t)N + nb) = o;
      } else {
        uint2 w; w.x = pk2bf(v[0], v[1]); w.y = pk2bf(v[2], v[3]);
        *(uint2*)(C + m * (size_t)N + nb) = w;
      }
    }
  }
}

// ---------------- flash attention v2: block = 128 q-rows of one (b,h), 4 waves -------
__global__ __launch_bounds__(256, 3)
void attn_kernel(const bf16* __restrict__ QK, const bf16* __restrict__ Vp,
                 bf16* __restrict__ O)
{
  const int tid  = threadIdx.x;
  const int wave = tid >> 6;
  const int lane = tid & 63;
  const int l15 = lane & 15;
  const int qd  = lane >> 4;

  // bijective XCD-chunked block swizzle: 768 blocks, 8 XCDs, 96 blocks/XCD
  int bid = blockIdx.y * gridDim.x + blockIdx.x;
  bid = (bid & 7) * 96 + (bid >> 3);
  const int bh = bid >> 4;                       // 0..47
  const int b  = bh / H_;
  const int h  = bh % H_;
  const int q0 = (bid & 15) * 128 + wave * 32;   // this wave's first q-row

  const bf16* Qb = QK + (size_t)b * S_ * SQK + h * HD_;
  const bf16* Kb = Qb + D_;                       // K block lives at col+768
  const bf16* Vb = Vp + (size_t)bh * 256 * 512;

  __shared__ __align__(16) bf16 Ks[2][64 * 64];             // 8 KB x2, chunk ^= row&7
  __shared__ __align__(16) bf16 Vs[2][8 * 512];             // 8 KB x2, packed V tile
  __shared__ __align__(16) unsigned short Pl[4][32 * PSTR]; // 18 KB, per-wave private
  unsigned short* Pw = &Pl[wave][0];

  // staging coords: per 256-thread pass, row = tid>>3 (0..31), chunk = tid&7
  const int srow = tid >> 3;
  const int sch  = (tid & 7) ^ (srow & 7);       // pre-swizzled source chunk
  const bf16* Kst = Kb + (size_t)srow * SQK + sch * 8;
  const bf16* Vst = Vb + tid * 8;

  uint4 qf[2][2];
#pragma unroll
  for (int mt = 0; mt < 2; ++mt)
#pragma unroll
    for (int ks = 0; ks < 2; ++ks)
      qf[mt][ks] = *(const uint4*)(Qb + (size_t)(q0 + mt * 16 + l15) * SQK + ks * 32 + qd * 8);

  f32x4 o_[2][5];                               // [..][4] = ones-column row-sums (l)
#pragma unroll
  for (int mt = 0; mt < 2; ++mt)
#pragma unroll
    for (int dt = 0; dt < 5; ++dt) o_[mt][dt] = zero4();

  // constant ones-column B fragment: B[k][n] = (n==0) ? 1 : 0
  uint4 vones;
  { const unsigned v = (l15 == 0) ? 0x3F803F80u : 0u; vones.x = v; vones.y = v; vones.z = v; vones.w = v; }

  const float C1 = 1.4426950408889634f * 0.125f;   // log2e / 8
  const float C0 = -12.0f * 1.4426950408889634f;   // -M0 * log2e

  // prologue: stage tile 0 into buffer 0
  load_lds16(Kst,                      &Ks[0][tid * 8]);
  load_lds16(Kst + (size_t)32 * SQK,   &Ks[0][2048 + tid * 8]);
  load_lds16(Vst,                      &Vs[0][tid * 8]);
  load_lds16(Vst + 2048,               &Vs[0][2048 + tid * 8]);
  __syncthreads();                                 // drains vmcnt(0)

  for (int sk = 0; sk < S_; sk += 64) {
    const int cur = (sk >> 6) & 1;
    const bf16* Ksc = &Ks[cur][0];
    const bf16* Vsc = &Vs[cur][0];

    // --- LDS reads FIRST ---
    uint4 kf[4][2];
#pragma unroll
    for (int kt = 0; kt < 4; ++kt)
#pragma unroll
      for (int ks = 0; ks < 2; ++ks)
        kf[kt][ks] = *(const uint4*)(Ksc + (size_t)(kt * 16 + l15) * 64
                                         + ((ks * 4 + qd) ^ (l15 & 7)) * 8);
    uint4 vf[2][4];
#pragma unroll
    for (int ks = 0; ks < 2; ++ks)
#pragma unroll
      for (int dt = 0; dt < 4; ++dt)
        vf[ks][dt] = *(const uint4*)(Vsc + (ks * 4 + qd) * 512 + (dt * 16 + l15) * 8);

    // --- async-stage next tile; latency hidden under this step's compute ---
    if (sk + 64 < S_) {
      const int nxt = cur ^ 1;
      const bf16* Kn = Kst + (size_t)(sk + 64) * SQK;
      const bf16* Vn = Vst + (size_t)(sk + 64) * 64;
      load_lds16(Kn,                    &Ks[nxt][tid * 8]);
      load_lds16(Kn + (size_t)32 * SQK, &Ks[nxt][2048 + tid * 8]);
      load_lds16(Vn,                    &Vs[nxt][tid * 8]);
      load_lds16(Vn + 2048,             &Vs[nxt][2048 + tid * 8]);
    }

    // --- S^T[key][q] = K·Q^T ---
    f32x4 st[4][2];
#pragma unroll
    for (int kt = 0; kt < 4; ++kt)
#pragma unroll
      for (int mt = 0; mt < 2; ++mt) st[kt][mt] = zero4();
    __builtin_amdgcn_s_setprio(1);
#pragma unroll
    for (int ks = 0; ks < 2; ++ks)
#pragma unroll
      for (int kt = 0; kt < 4; ++kt)
#pragma unroll
        for (int mt = 0; mt < 2; ++mt)
          st[kt][mt] = mfma16(kf[kt][ks], qf[mt][ks], st[kt][mt]);
    __builtin_amdgcn_s_setprio(0);

    // --- p = exp2(fma(s,C1,C0)); 4 consecutive keys/lane -> one b64 LDS write ---
#pragma unroll
    for (int mt = 0; mt < 2; ++mt) {
      unsigned short* prow = Pw + (mt * 16 + l15) * PSTR;
#pragma unroll
      for (int kt = 0; kt < 4; ++kt) {
        const float p0 = __builtin_amdgcn_exp2f(fmaf(st[kt][mt][0], C1, C0));
        const float p1 = __builtin_amdgcn_exp2f(fmaf(st[kt][mt][1], C1, C0));
        const float p2 = __builtin_amdgcn_exp2f(fmaf(st[kt][mt][2], C1, C0));
        const float p3 = __builtin_amdgcn_exp2f(fmaf(st[kt][mt][3], C1, C0));
        uint2 w; w.x = pk2bf(p0, p1); w.y = pk2bf(p2, p3);
        *(uint2*)(prow + kt * 16 + qd * 4) = w;
      }
    }

    // --- read P as A-fragments (same wave; DS in-order) ---
    uint4 pf[2][2];
#pragma unroll
    for (int mt = 0; mt < 2; ++mt)
#pragma unroll
      for (int ks = 0; ks < 2; ++ks)
        pf[mt][ks] = *(const uint4*)(Pw + (mt * 16 + l15) * PSTR + ks * 32 + qd * 8);

    // --- O += P V ; l += P * ones ---
    __builtin_amdgcn_s_setprio(1);
#pragma unroll
    for (int ks = 0; ks < 2; ++ks)
#pragma unroll
      for (int mt = 0; mt < 2; ++mt) {
#pragma unroll
        for (int dt = 0; dt < 4; ++dt)
          o_[mt][dt] = mfma16(pf[mt][ks], vf[ks][dt], o_[mt][dt]);
        o_[mt][4] = mfma16(pf[mt][ks], vones, o_[mt][4]);
      }
    __builtin_amdgcn_s_setprio(0);

    // barrier: all waves done reading buf[cur]; stage for buf[nxt] drained here
    __syncthreads();
  }

  // --- epilogue: O / l  -> o_buf[b, s, h*64 + e]; l lives on l15==0 lanes ---
  const size_t tok0 = (size_t)b * S_ + q0;
#pragma unroll
  for (int mt = 0; mt < 2; ++mt) {
#pragma unroll
    for (int r = 0; r < 4; ++r) {
      const float lr = __shfl(o_[mt][4][r], (lane & 48), 64);
      const float inv = __builtin_amdgcn_rcpf(lr);
      const size_t row = tok0 + mt * 16 + qd * 4 + r;
#pragma unroll
      for (int dt = 0; dt < 4; ++dt)
        O[row * D_ + h * HD_ + dt * 16 + l15] = f2b_fast(o_[mt][dt][r] * inv);
    }
  }
}

// ---------------- orchestration ----------------
extern "C" void kernel_launch(void* const* d_in, const int* in_sizes, int n_in,
                              void* d_out, int out_size, void* d_ws, size_t ws_size,
                              hipStream_t stream)
{
  const float* x   = (const float*)d_in[0];
  const float* Wq  = (const float*)d_in[1];
  const float* bq  = (const float*)d_in[2];
  const float* Wk  = (const float*)d_in[3];
  const float* bk  = (const float*)d_in[4];
  const float* Wv  = (const float*)d_in[5];
  const float* bv  = (const float*)d_in[6];
  const float* Wo  = (const float*)d_in[7];
  const float* bo  = (const float*)d_in[8];
  const float* W1  = (const float*)d_in[9];
  const float* b1  = (const float*)d_in[10];
  const float* W2  = (const float*)d_in[11];
  const float* b2  = (const float*)d_in[12];
  const float* g1  = (const float*)d_in[13];
  const float* be1 = (const float*)d_in[14];
  const float* g2  = (const float*)d_in[15];
  const float* be2 = (const float*)d_in[16];

  // full-M FFN needs 77,079,552 B of workspace; otherwise split (64,496,640 B)
  const bool full = ws_size >= (size_t)77079552;

  char* ws = (char*)d_ws;
  bf16* qk     = (bf16*)(ws + 0);           // QKV gemm -> attn
  bf16* vp     = (bf16*)(ws + 25165824);    // QKV gemm -> attn
  bf16* h1     = (bf16*)(ws + 37748736);    // LN1 -> QKV gemm
  bf16* obuf   = h1;                        // attn -> O-proj (h1 dead)
  bf16* abuf   = (bf16*)(ws + 0);           // O-proj -> LN2 (qk dead)
  bf16* h2     = (bf16*)(ws + (full ? 50331648u : 25165824u));  // LN2 -> FFN1
  bf16* fbuf   = (bf16*)(ws + 0);           // FFN1 -> FFN2 (full: 48 MB; split: 24 MB)
  const size_t wb = full ? 62914560u : 50331648u;
  bf16* wqkv_p = (bf16*)(ws + wb);                    // 3,538,944 B
  bf16* wo_p   = (bf16*)(ws + wb + 3538944u);         // 1,179,648 B
  bf16* w1_p   = (bf16*)(ws + wb + 4718592u);         // 4,718,592 B
  bf16* w2_p   = (bf16*)(ws + wb + 9437184u);         // 4,718,592 B
  float* bqkvf = (float*)(ws + wb + 14155776u);       // 9,216 B

  float* outp = (float*)d_out;

  repack_all<<<dim3(3465), dim3(256), 0, stream>>>(Wq, Wk, Wv, Wo, W1, W2,
                                                   bq, bk, bv,
                                                   wqkv_p, wo_p, w1_p, w2_p, bqkvf);

  ln_x_kernel<<<dim3(BS_), dim3(256), 0, stream>>>(x, g1, be1, h1);
  gemm_lds<<<dim3(18, 64), dim3(256), 0, stream>>>(h1, wqkv_p, bqkvf, qk, vp, nullptr, 768, 2304, 0);
  attn_kernel<<<dim3(16, 48), dim3(256), 0, stream>>>(qk, vp, obuf);
  gemm_lds64<<<dim3(12, 64), dim3(256), 0, stream>>>(obuf, wo_p, bo, abuf, nullptr, 768, 768, 1);
  ln_h_kernel<<<dim3(BS_), dim3(256), 0, stream>>>(abuf, g2, be2, h2);

  if (full) {
    gemm_lds<<<dim3(24, 64), dim3(256), 0, stream>>>(h2, w1_p, b1, fbuf, nullptr, nullptr, 768, 3072, 2);
    gemm_lds64<<<dim3(12, 64), dim3(256), 0, stream>>>(fbuf, w2_p, b2, nullptr, outp, 3072, 768, 3);
  } else {
    gemm_lds<<<dim3(24, 32), dim3(256), 0, stream>>>(h2, w1_p, b1, fbuf, nullptr, nullptr, 768, 3072, 2);
    gemm_lds64<<<dim3(12, 32), dim3(256), 0, stream>>>(fbuf, w2_p, b2, nullptr, outp, 3072, 768, 3);
    gemm_lds<<<dim3(24, 32), dim3(256), 0, stream>>>(h2 + (size_t)4096 * D_, w1_p, b1, fbuf, nullptr, nullptr, 768, 3072, 2);
    gemm_lds64<<<dim3(12, 32), dim3(256), 0, stream>>>(fbuf, w2_p, b2, nullptr, outp + (size_t)4096 * D_, 3072, 768, 3);
  }
}

// Round 13
// 370.526 us; speedup vs baseline: 1.0823x; 1.0218x over previous
//
#include <hip/hip_runtime.h>
#include <hip/hip_bf16.h>
#include <math.h>

typedef __hip_bfloat16 bf16;
typedef __attribute__((ext_vector_type(8))) short short8;
typedef __attribute__((ext_vector_type(4))) float f32x4;

#define D_  768
#define H_  12
#define HD_ 64
#define F_  3072
#define B_  4
#define S_  2048
#define BS_ (B_*S_)
#define SQK 1536   // Q,K buffer row stride (V lives in packed Vp)
#define PSTR 72    // P LDS row stride in u16 (64 + 8 pad; 144 B = 16B-aligned rows)

__device__ __forceinline__ float b2f(bf16 x){ return __bfloat162float(x); }

union BU { bf16 b; unsigned short u; };
// fast bf16 round (half-away ties; inputs are finite, non-NaN)
__device__ __forceinline__ bf16 f2b_fast(float x){
  BU t; t.u = (unsigned short)((__float_as_uint(x) + 0x8000u) >> 16); return t.b;
}
// pack two floats -> bf16x2 dword (low u16 = a)
__device__ __forceinline__ unsigned pk2bf(float a, float b){
  return __builtin_amdgcn_perm(__float_as_uint(b) + 0x8000u,
                               __float_as_uint(a) + 0x8000u, 0x07060302u);
}

__device__ __forceinline__ f32x4 zero4(){ f32x4 z; z.x=0.f; z.y=0.f; z.z=0.f; z.w=0.f; return z; }

__device__ __forceinline__ f32x4 mfma16(uint4 a, uint4 b, f32x4 c){
  union U { uint4 u; short8 s; };
  U A, B; A.u = a; B.u = b;
  return __builtin_amdgcn_mfma_f32_16x16x32_bf16(A.s, B.s, c, 0, 0, 0);
}

// async global->LDS, 16 B per lane (global_load_lds_dwordx4)
typedef const __attribute__((address_space(1))) void gvoid;
typedef __attribute__((address_space(3))) void lvoid;
__device__ __forceinline__ void load_lds16(const void* g, void* l){
  __builtin_amdgcn_global_load_lds((gvoid*)g, (lvoid*)l, 16, 0, 0);
}

// exact-accuracy GELU via A&S 7.1.26 erf (|eps| <= 1.5e-7), HW exp/rcp
__device__ __forceinline__ float fast_gelu(float v){
  const float x = v * 0.70710678118654752f;
  const float ax = fabsf(x);
  const float t = __builtin_amdgcn_rcpf(fmaf(0.3275911f, ax, 1.0f));
  const float poly = t * fmaf(t, fmaf(t, fmaf(t, fmaf(t, 1.061405429f, -1.453152027f),
                                              1.421413741f), -0.284496736f), 0.254829592f);
  const float e = __builtin_amdgcn_exp2f(ax * ax * -1.4426950408889634f);
  const float erfax = 1.0f - poly * e;
  const float erfx = copysignf(erfax, x);
  return 0.5f * v * (1.0f + erfx);
}

// ------------- weight repack body (fp32 -> bf16 W^T): Wt[n][k] = W[k][n] -----------
__device__ __forceinline__ void repack_body(const float* __restrict__ W,
                                            bf16* __restrict__ Wt, int K, int N, int t)
{
  const int n = t % N;
  const int kg = t / N;
  const float* src = W + (size_t)kg * 8 * N + n;
  union { unsigned u32[4]; uint4 u; } pk;
#pragma unroll
  for (int j = 0; j < 4; ++j)
    pk.u32[j] = pk2bf(src[(size_t)(2 * j) * N], src[(size_t)(2 * j + 1) * N]);
  *(uint4*)(Wt + ((size_t)n * (K >> 3) + kg) * 8) = pk.u;
}

// ------------- single prep kernel: all weight repacks + bias concat ----------------
// blocks [0,864): QKV combined W^T; [864,1152): Wo; [1152,2304): W1; [2304,3456): W2;
// [3456,3465): bias concat. Per-branch bodies are byte-exact ports of the previous
// standalone kernels.
__global__ __launch_bounds__(256)
void repack_all(const float* __restrict__ Wq, const float* __restrict__ Wk,
                const float* __restrict__ Wv, const float* __restrict__ Wo,
                const float* __restrict__ W1, const float* __restrict__ W2,
                const float* __restrict__ bq, const float* __restrict__ bk,
                const float* __restrict__ bv,
                bf16* __restrict__ wqkv_p, bf16* __restrict__ wo_p,
                bf16* __restrict__ w1_p, bf16* __restrict__ w2_p,
                float* __restrict__ bqkvf)
{
  const int bid = blockIdx.x;
  if (bid < 864) {
    // QKV combined W^T: rows n in [0,2304): sel=n/768, h=(n%768)>>6, e=n&63; K=768
    const int t = bid * 256 + threadIdx.x;        // 864*256 = 96*2304 exact
    const int n = t % 2304;
    const int kg = t / 2304;                      // 0..95
    const int sel = n / 768;
    const int nn = n - sel * 768;
    const int hh = nn >> 6;
    const int ee = nn & 63;
    const float* W = (sel == 0) ? Wq : (sel == 1) ? Wk : Wv;
    const float* src = W + ((size_t)hh * 768 + (size_t)kg * 8) * 64 + ee;
    union { unsigned u32[4]; uint4 u; } pk;
#pragma unroll
    for (int j = 0; j < 4; ++j)
      pk.u32[j] = pk2bf(src[(size_t)(2 * j) * 64], src[(size_t)(2 * j + 1) * 64]);
    *(uint4*)(wqkv_p + ((size_t)n * 96 + kg) * 8) = pk.u;
  } else if (bid < 1152) {
    repack_body(Wo, wo_p, 768, 768, (bid - 864) * 256 + threadIdx.x);
  } else if (bid < 2304) {
    repack_body(W1, w1_p, 768, 3072, (bid - 1152) * 256 + threadIdx.x);
  } else if (bid < 3456) {
    repack_body(W2, w2_p, 3072, 768, (bid - 2304) * 256 + threadIdx.x);
  } else {
    const int t = (bid - 3456) * 256 + threadIdx.x;   // 9*256 = 2304 exact
    bqkvf[t] = (t < 768) ? bq[t] : (t < 1536) ? bk[t - 768] : bv[t - 1536];
  }
}

// ------------- LayerNorm v2: ONE WAVE PER ROW, 4 rows/block, no barriers/LDS -------
// Lane l covers 12 elements via 3 coalesced f32x4 passes (cols p*256 + l*4);
// mean/var via pure __shfl_xor wave reductions; bf16x4 packed stores.
__global__ __launch_bounds__(256)
void ln_x_kernel(const float* __restrict__ X, const float* __restrict__ G,
                 const float* __restrict__ Bet, bf16* __restrict__ Y)
{
  const int wv = threadIdx.x >> 6;              // wave 0..3
  const int ln = threadIdx.x & 63;
  const size_t row = (size_t)blockIdx.x * 4 + wv;
  const float* x = X + row * D_;
  f32x4 v[3];
#pragma unroll
  for (int p = 0; p < 3; ++p)
    v[p] = *(const f32x4*)(x + p * 256 + ln * 4);
  float s = 0.f;
#pragma unroll
  for (int p = 0; p < 3; ++p) s += v[p].x + v[p].y + v[p].z + v[p].w;
#pragma unroll
  for (int d = 32; d >= 1; d >>= 1) s += __shfl_xor(s, d, 64);
  const float mu = s * (1.0f / 768.0f);
  float sq = 0.f;
#pragma unroll
  for (int p = 0; p < 3; ++p) {
    v[p].x -= mu; v[p].y -= mu; v[p].z -= mu; v[p].w -= mu;
    sq += v[p].x * v[p].x + v[p].y * v[p].y + v[p].z * v[p].z + v[p].w * v[p].w;
  }
#pragma unroll
  for (int d = 32; d >= 1; d >>= 1) sq += __shfl_xor(sq, d, 64);
  const float rs = rsqrtf(sq * (1.0f / 768.0f) + 1e-5f);
  bf16* y = Y + row * D_;
#pragma unroll
  for (int p = 0; p < 3; ++p) {
    const f32x4 g4 = *(const f32x4*)(G   + p * 256 + ln * 4);
    const f32x4 b4 = *(const f32x4*)(Bet + p * 256 + ln * 4);
    uint2 w;
    w.x = pk2bf(fmaf(v[p].x * rs, g4.x, b4.x), fmaf(v[p].y * rs, g4.y, b4.y));
    w.y = pk2bf(fmaf(v[p].z * rs, g4.z, b4.z), fmaf(v[p].w * rs, g4.w, b4.w));
    *(uint2*)(y + p * 256 + ln * 4) = w;
  }
}

// LN over bf16 input (same structure; ushort4 loads):
__global__ __launch_bounds__(256)
void ln_h_kernel(const bf16* __restrict__ X, const float* __restrict__ G,
                 const float* __restrict__ Bet, bf16* __restrict__ Y)
{
  const int wv = threadIdx.x >> 6;
  const int ln = threadIdx.x & 63;
  const size_t row = (size_t)blockIdx.x * 4 + wv;
  const bf16* x = X + row * D_;
  f32x4 v[3];
#pragma unroll
  for (int p = 0; p < 3; ++p) {
    const ushort4 u = *(const ushort4*)(x + p * 256 + ln * 4);
    v[p].x = __uint_as_float((unsigned)u.x << 16);
    v[p].y = __uint_as_float((unsigned)u.y << 16);
    v[p].z = __uint_as_float((unsigned)u.z << 16);
    v[p].w = __uint_as_float((unsigned)u.w << 16);
  }
  float s = 0.f;
#pragma unroll
  for (int p = 0; p < 3; ++p) s += v[p].x + v[p].y + v[p].z + v[p].w;
#pragma unroll
  for (int d = 32; d >= 1; d >>= 1) s += __shfl_xor(s, d, 64);
  const float mu = s * (1.0f / 768.0f);
  float sq = 0.f;
#pragma unroll
  for (int p = 0; p < 3; ++p) {
    v[p].x -= mu; v[p].y -= mu; v[p].z -= mu; v[p].w -= mu;
    sq += v[p].x * v[p].x + v[p].y * v[p].y + v[p].z * v[p].z + v[p].w * v[p].w;
  }
#pragma unroll
  for (int d = 32; d >= 1; d >>= 1) sq += __shfl_xor(sq, d, 64);
  const float rs = rsqrtf(sq * (1.0f / 768.0f) + 1e-5f);
  bf16* y = Y + row * D_;
#pragma unroll
  for (int p = 0; p < 3; ++p) {
    const f32x4 g4 = *(const f32x4*)(G   + p * 256 + ln * 4);
    const f32x4 b4 = *(const f32x4*)(Bet + p * 256 + ln * 4);
    uint2 w;
    w.x = pk2bf(fmaf(v[p].x * rs, g4.x, b4.x), fmaf(v[p].y * rs, g4.y, b4.y));
    w.y = pk2bf(fmaf(v[p].z * rs, g4.z, b4.z), fmaf(v[p].w * rs, g4.w, b4.w));
    *(uint2*)(y + p * 256 + ln * 4) = w;
  }
}

// ------------- LDS-staged GEMM 128x128 (R4-exact): double-buffered prefetch,
// XCD swizzle, both-sides bank swizzle (chunk ^= (row>>1)&3), ds_reads-first,
// direct epilogue. modes: 0 QKV epilogue (qk/Vp), 1 bf16 C, 2 GELU bf16 C,
// 3 fp32 Cf (+bias)
__global__ __launch_bounds__(256)
void gemm_lds(const bf16* __restrict__ A, const bf16* __restrict__ Wt,
              const float* __restrict__ bias, bf16* __restrict__ C,
              bf16* __restrict__ Vp, float* __restrict__ Cf,
              int K, int N, int mode)
{
  __shared__ __align__(16) bf16 As[2][128 * 32];   // [buf][row][k], 64 B rows
  __shared__ __align__(16) bf16 Bs[2][128 * 32];

  const int tid = threadIdx.x;
  const int wave = tid >> 6, lane = tid & 63;
  const int l15 = lane & 15, qd = lane >> 4;
  const int wy = wave >> 1, wx = wave & 1;

  // bijective XCD-chunked swizzle (all grids divisible by 8)
  int id = (int)blockIdx.y * (int)gridDim.x + (int)blockIdx.x;
  const int chunk = ((int)gridDim.x * (int)gridDim.y) >> 3;
  id = (id & 7) * chunk + (id >> 3);
  const int bx = id % (int)gridDim.x;
  const int by = id / (int)gridDim.x;

  const size_t m0 = (size_t)by * 128;
  const int n0 = bx * 128;

  const int r0 = tid >> 2, c0 = tid & 3;        // row 0..63, kchunk 0..3
  const int c0s = c0 ^ ((r0 >> 1) & 3);         // bank-swizzled source chunk
  const bf16* Ag0 = A  + (m0 + r0) * (size_t)K + c0s * 8;
  const bf16* Ag1 = A  + (m0 + r0 + 64) * (size_t)K + c0s * 8;
  const bf16* Bg0 = Wt + (size_t)(n0 + r0) * K + c0s * 8;
  const bf16* Bg1 = Wt + (size_t)(n0 + r0 + 64) * K + c0s * 8;

  f32x4 acc[4][4];                               // [nt][mt]
#pragma unroll
  for (int i = 0; i < 4; ++i)
#pragma unroll
    for (int j = 0; j < 4; ++j) acc[i][j] = zero4();

  const int arow = wy * 64;
  const int brow = wx * 64;
  const int ksw = (l15 >> 1) & 3;                // read-side chunk XOR

  // prologue: stage k-tile 0 into buffer 0
  load_lds16(Ag0, &As[0][(size_t)tid * 8]);
  load_lds16(Ag1, &As[0][(size_t)(tid + 256) * 8]);
  load_lds16(Bg0, &Bs[0][(size_t)tid * 8]);
  load_lds16(Bg1, &Bs[0][(size_t)(tid + 256) * 8]);
  __syncthreads();

  for (int k0 = 0; k0 < K; k0 += 32) {
    const int cur = (k0 >> 5) & 1;
    // fragment reads FIRST (alias ordering: no vmcnt wait ahead of ds_read)
    uint4 af[4], bfr[4];
#pragma unroll
    for (int mt = 0; mt < 4; ++mt)
      af[mt] = *(const uint4*)(&As[cur][0] + (size_t)(arow + mt * 16 + l15) * 32 + (qd ^ ksw) * 8);
#pragma unroll
    for (int nt = 0; nt < 4; ++nt)
      bfr[nt] = *(const uint4*)(&Bs[cur][0] + (size_t)(brow + nt * 16 + l15) * 32 + (qd ^ ksw) * 8);
    if (k0 + 32 < K) {
      const int nxt = cur ^ 1;
      load_lds16(Ag0 + k0 + 32, &As[nxt][(size_t)tid * 8]);
      load_lds16(Ag1 + k0 + 32, &As[nxt][(size_t)(tid + 256) * 8]);
      load_lds16(Bg0 + k0 + 32, &Bs[nxt][(size_t)tid * 8]);
      load_lds16(Bg1 + k0 + 32, &Bs[nxt][(size_t)(tid + 256) * 8]);
    }
#pragma unroll
    for (int nt = 0; nt < 4; ++nt)
#pragma unroll
      for (int mt = 0; mt < 4; ++mt)
        acc[nt][mt] = mfma16(bfr[nt], af[mt], acc[nt][mt]);   // C^T
    __syncthreads();   // drains prefetch vmcnt + all waves done reading buf[cur]
  }

  // epilogue: D row = out col n = brow+nt*16+qd*4+r (4 consecutive), D col = token m
  const size_t wm0 = m0 + arow;
  const int wn0 = n0 + brow;
#pragma unroll
  for (int nt = 0; nt < 4; ++nt) {
    const int nb = wn0 + nt * 16 + qd * 4;
    const f32x4 bs4 = *(const f32x4*)(bias + nb);
#pragma unroll
    for (int mt = 0; mt < 4; ++mt) {
      const size_t m = wm0 + mt * 16 + l15;
      float v[4];
#pragma unroll
      for (int r = 0; r < 4; ++r) v[r] = acc[nt][mt][r] + bs4[r];
      if (mode == 2) {
#pragma unroll
        for (int r = 0; r < 4; ++r) v[r] = fast_gelu(v[r]);
      }
      if (mode == 3) {
        f32x4 o; o.x = v[0]; o.y = v[1]; o.z = v[2]; o.w = v[3];
        *(f32x4*)(Cf + m * (size_t)N + nb) = o;
      } else if (mode == 0) {
        if (nb < SQK) {
          uint2 w; w.x = pk2bf(v[0], v[1]); w.y = pk2bf(v[2], v[3]);
          *(uint2*)(C + m * SQK + nb) = w;
        } else {
          const int bb = (int)(m >> 11);
          const int ss = (int)(m & 2047);
          const int hh = (nb - SQK) >> 6;
          const size_t vbase = (((size_t)bb * H_ + hh) * 256 + (ss >> 3)) * 512 + (ss & 7);
#pragma unroll
          for (int r = 0; r < 4; ++r)
            Vp[vbase + (size_t)((nb & 63) + r) * 8] = f2b_fast(v[r]);   // Vp[b][h][s/8][e][s&7]
        }
      } else {
        uint2 w; w.x = pk2bf(v[0], v[1]); w.y = pk2bf(v[2], v[3]);
        *(uint2*)(C + m * (size_t)N + nb) = w;
      }
    }
  }
}

// ------------- LDS-staged GEMM 128Mx64N, BK=64: for N=768 outputs (O-proj, FFN2) ----
// grid (12, M/128) = 768 blocks -> exactly 3 blocks/CU. BK=64 halves barrier count.
// 128 B LDS rows, both-sides XOR chunk swizzle (chunk ^= row&7): conflict-free.
// modes: 1 bf16 C, 3 fp32 Cf (+bias). LDS 48 KB (double-buffered) -> 3 blocks/CU.
__global__ __launch_bounds__(256)
void gemm_lds64(const bf16* __restrict__ A, const bf16* __restrict__ Wt,
                const float* __restrict__ bias, bf16* __restrict__ C,
                float* __restrict__ Cf, int K, int N, int mode)
{
  __shared__ __align__(16) bf16 As[2][128 * 64];   // 16 KB per buf
  __shared__ __align__(16) bf16 Bs[2][64 * 64];    //  8 KB per buf

  const int tid = threadIdx.x;
  const int wave = tid >> 6, lane = tid & 63;
  const int l15 = lane & 15, qd = lane >> 4;

  int id = (int)blockIdx.y * (int)gridDim.x + (int)blockIdx.x;
  const int chunk = ((int)gridDim.x * (int)gridDim.y) >> 3;
  id = (id & 7) * chunk + (id >> 3);
  const int bx = id % (int)gridDim.x;
  const int by = id / (int)gridDim.x;

  const size_t m0 = (size_t)by * 128;
  const int n0 = bx * 64;

  // staging: row = tid>>3 (0..31, +32/pass), chunk = tid&7; source chunk pre-swizzled
  const int srow = tid >> 3;
  const int sch  = (tid & 7) ^ (srow & 7);
  const bf16* Ag = A  + (m0 + srow) * (size_t)K + sch * 8;
  const bf16* Bg = Wt + (size_t)(n0 + srow) * K + sch * 8;

  f32x4 acc[4][2];                               // [nt][mt]
#pragma unroll
  for (int i = 0; i < 4; ++i)
#pragma unroll
    for (int j = 0; j < 2; ++j) acc[i][j] = zero4();

  const int arow = wave * 32;
  const int ksw = l15 & 7;                       // read-side chunk XOR

  // prologue: stage k-tile 0 into buffer 0 (A: 4 passes, B: 2 passes)
#pragma unroll
  for (int p = 0; p < 4; ++p)
    load_lds16(Ag + (size_t)32 * p * K, &As[0][(size_t)(tid + 256 * p) * 8]);
#pragma unroll
  for (int p = 0; p < 2; ++p)
    load_lds16(Bg + (size_t)32 * p * K, &Bs[0][(size_t)(tid + 256 * p) * 8]);
  __syncthreads();

  for (int k0 = 0; k0 < K; k0 += 64) {
    const int cur = (k0 >> 6) & 1;
    // fragment reads FIRST
    uint4 af[2][2], bfr[4][2];
#pragma unroll
    for (int mt = 0; mt < 2; ++mt)
#pragma unroll
      for (int ks = 0; ks < 2; ++ks)
        af[mt][ks] = *(const uint4*)(&As[cur][0]
                       + (size_t)(arow + mt * 16 + l15) * 64 + ((ks * 4 + qd) ^ ksw) * 8);
#pragma unroll
    for (int nt = 0; nt < 4; ++nt)
#pragma unroll
      for (int ks = 0; ks < 2; ++ks)
        bfr[nt][ks] = *(const uint4*)(&Bs[cur][0]
                       + (size_t)(nt * 16 + l15) * 64 + ((ks * 4 + qd) ^ ksw) * 8);
    if (k0 + 64 < K) {
      const int nxt = cur ^ 1;
#pragma unroll
      for (int p = 0; p < 4; ++p)
        load_lds16(Ag + (size_t)32 * p * K + k0 + 64, &As[nxt][(size_t)(tid + 256 * p) * 8]);
#pragma unroll
      for (int p = 0; p < 2; ++p)
        load_lds16(Bg + (size_t)32 * p * K + k0 + 64, &Bs[nxt][(size_t)(tid + 256 * p) * 8]);
    }
#pragma unroll
    for (int ks = 0; ks < 2; ++ks)
#pragma unroll
      for (int nt = 0; nt < 4; ++nt)
#pragma unroll
        for (int mt = 0; mt < 2; ++mt)
          acc[nt][mt] = mfma16(bfr[nt][ks], af[mt][ks], acc[nt][mt]);   // C^T
    __syncthreads();
  }

  const size_t wm0 = m0 + arow;
#pragma unroll
  for (int nt = 0; nt < 4; ++nt) {
    const int nb = n0 + nt * 16 + qd * 4;
    const f32x4 bs4 = *(const f32x4*)(bias + nb);
#pragma unroll
    for (int mt = 0; mt < 2; ++mt) {
      const size_t m = wm0 + mt * 16 + l15;
      float v[4];
#pragma unroll
      for (int r = 0; r < 4; ++r) v[r] = acc[nt][mt][r] + bs4[r];
      if (mode == 3) {
        f32x4 o; o.x = v[0]; o.y = v[1]; o.z = v[2]; o.w = v[3];
        *(f32x4*)(Cf + m * (size_t)N + nb) = o;
      } else {
        uint2 w; w.x = pk2bf(v[0], v[1]); w.y = pk2bf(v[2], v[3]);
        *(uint2*)(C + m * (size_t)N + nb) = w;
      }
    }
  }
}

// ---------------- flash attention v2: block = 128 q-rows of one (b,h), 4 waves -------
__global__ __launch_bounds__(256, 3)
void attn_kernel(const bf16* __restrict__ QK, const bf16* __restrict__ Vp,
                 bf16* __restrict__ O)
{
  const int tid  = threadIdx.x;
  const int wave = tid >> 6;
  const int lane = tid & 63;
  const int l15 = lane & 15;
  const int qd  = lane >> 4;

  // bijective XCD-chunked block swizzle: 768 blocks, 8 XCDs, 96 blocks/XCD
  int bid = blockIdx.y * gridDim.x + blockIdx.x;
  bid = (bid & 7) * 96 + (bid >> 3);
  const int bh = bid >> 4;                       // 0..47
  const int b  = bh / H_;
  const int h  = bh % H_;
  const int q0 = (bid & 15) * 128 + wave * 32;   // this wave's first q-row

  const bf16* Qb = QK + (size_t)b * S_ * SQK + h * HD_;
  const bf16* Kb = Qb + D_;                       // K block lives at col+768
  const bf16* Vb = Vp + (size_t)bh * 256 * 512;

  __shared__ __align__(16) bf16 Ks[2][64 * 64];             // 8 KB x2, chunk ^= row&7
  __shared__ __align__(16) bf16 Vs[2][8 * 512];             // 8 KB x2, packed V tile
  __shared__ __align__(16) unsigned short Pl[4][32 * PSTR]; // 18 KB, per-wave private
  unsigned short* Pw = &Pl[wave][0];

  // staging coords: per 256-thread pass, row = tid>>3 (0..31), chunk = tid&7
  const int srow = tid >> 3;
  const int sch  = (tid & 7) ^ (srow & 7);       // pre-swizzled source chunk
  const bf16* Kst = Kb + (size_t)srow * SQK + sch * 8;
  const bf16* Vst = Vb + tid * 8;

  uint4 qf[2][2];
#pragma unroll
  for (int mt = 0; mt < 2; ++mt)
#pragma unroll
    for (int ks = 0; ks < 2; ++ks)
      qf[mt][ks] = *(const uint4*)(Qb + (size_t)(q0 + mt * 16 + l15) * SQK + ks * 32 + qd * 8);

  f32x4 o_[2][5];                               // [..][4] = ones-column row-sums (l)
#pragma unroll
  for (int mt = 0; mt < 2; ++mt)
#pragma unroll
    for (int dt = 0; dt < 5; ++dt) o_[mt][dt] = zero4();

  // constant ones-column B fragment: B[k][n] = (n==0) ? 1 : 0
  uint4 vones;
  { const unsigned v = (l15 == 0) ? 0x3F803F80u : 0u; vones.x = v; vones.y = v; vones.z = v; vones.w = v; }

  const float C1 = 1.4426950408889634f * 0.125f;   // log2e / 8
  const float C0 = -12.0f * 1.4426950408889634f;   // -M0 * log2e

  // prologue: stage tile 0 into buffer 0
  load_lds16(Kst,                      &Ks[0][tid * 8]);
  load_lds16(Kst + (size_t)32 * SQK,   &Ks[0][2048 + tid * 8]);
  load_lds16(Vst,                      &Vs[0][tid * 8]);
  load_lds16(Vst + 2048,               &Vs[0][2048 + tid * 8]);
  __syncthreads();                                 // drains vmcnt(0)

  for (int sk = 0; sk < S_; sk += 64) {
    const int cur = (sk >> 6) & 1;
    const bf16* Ksc = &Ks[cur][0];
    const bf16* Vsc = &Vs[cur][0];

    // --- LDS reads FIRST ---
    uint4 kf[4][2];
#pragma unroll
    for (int kt = 0; kt < 4; ++kt)
#pragma unroll
      for (int ks = 0; ks < 2; ++ks)
        kf[kt][ks] = *(const uint4*)(Ksc + (size_t)(kt * 16 + l15) * 64
                                         + ((ks * 4 + qd) ^ (l15 & 7)) * 8);
    uint4 vf[2][4];
#pragma unroll
    for (int ks = 0; ks < 2; ++ks)
#pragma unroll
      for (int dt = 0; dt < 4; ++dt)
        vf[ks][dt] = *(const uint4*)(Vsc + (ks * 4 + qd) * 512 + (dt * 16 + l15) * 8);

    // --- async-stage next tile; latency hidden under this step's compute ---
    if (sk + 64 < S_) {
      const int nxt = cur ^ 1;
      const bf16* Kn = Kst + (size_t)(sk + 64) * SQK;
      const bf16* Vn = Vst + (size_t)(sk + 64) * 64;
      load_lds16(Kn,                    &Ks[nxt][tid * 8]);
      load_lds16(Kn + (size_t)32 * SQK, &Ks[nxt][2048 + tid * 8]);
      load_lds16(Vn,                    &Vs[nxt][tid * 8]);
      load_lds16(Vn + 2048,             &Vs[nxt][2048 + tid * 8]);
    }

    // --- S^T[key][q] = K·Q^T ---
    f32x4 st[4][2];
#pragma unroll
    for (int kt = 0; kt < 4; ++kt)
#pragma unroll
      for (int mt = 0; mt < 2; ++mt) st[kt][mt] = zero4();
    __builtin_amdgcn_s_setprio(1);
#pragma unroll
    for (int ks = 0; ks < 2; ++ks)
#pragma unroll
      for (int kt = 0; kt < 4; ++kt)
#pragma unroll
        for (int mt = 0; mt < 2; ++mt)
          st[kt][mt] = mfma16(kf[kt][ks], qf[mt][ks], st[kt][mt]);
    __builtin_amdgcn_s_setprio(0);

    // --- p = exp2(fma(s,C1,C0)); 4 consecutive keys/lane -> one b64 LDS write ---
#pragma unroll
    for (int mt = 0; mt < 2; ++mt) {
      unsigned short* prow = Pw + (mt * 16 + l15) * PSTR;
#pragma unroll
      for (int kt = 0; kt < 4; ++kt) {
        const float p0 = __builtin_amdgcn_exp2f(fmaf(st[kt][mt][0], C1, C0));
        const float p1 = __builtin_amdgcn_exp2f(fmaf(st[kt][mt][1], C1, C0));
        const float p2 = __builtin_amdgcn_exp2f(fmaf(st[kt][mt][2], C1, C0));
        const float p3 = __builtin_amdgcn_exp2f(fmaf(st[kt][mt][3], C1, C0));
        uint2 w; w.x = pk2bf(p0, p1); w.y = pk2bf(p2, p3);
        *(uint2*)(prow + kt * 16 + qd * 4) = w;
      }
    }

    // --- read P as A-fragments (same wave; DS in-order) ---
    uint4 pf[2][2];
#pragma unroll
    for (int mt = 0; mt < 2; ++mt)
#pragma unroll
      for (int ks = 0; ks < 2; ++ks)
        pf[mt][ks] = *(const uint4*)(Pw + (mt * 16 + l15) * PSTR + ks * 32 + qd * 8);

    // --- O += P V ; l += P * ones ---
    __builtin_amdgcn_s_setprio(1);
#pragma unroll
    for (int ks = 0; ks < 2; ++ks)
#pragma unroll
      for (int mt = 0; mt < 2; ++mt) {
#pragma unroll
        for (int dt = 0; dt < 4; ++dt)
          o_[mt][dt] = mfma16(pf[mt][ks], vf[ks][dt], o_[mt][dt]);
        o_[mt][4] = mfma16(pf[mt][ks], vones, o_[mt][4]);
      }
    __builtin_amdgcn_s_setprio(0);

    // barrier: all waves done reading buf[cur]; stage for buf[nxt] drained here
    __syncthreads();
  }

  // --- epilogue: O / l  -> o_buf[b, s, h*64 + e]; l lives on l15==0 lanes ---
  const size_t tok0 = (size_t)b * S_ + q0;
#pragma unroll
  for (int mt = 0; mt < 2; ++mt) {
#pragma unroll
    for (int r = 0; r < 4; ++r) {
      const float lr = __shfl(o_[mt][4][r], (lane & 48), 64);
      const float inv = __builtin_amdgcn_rcpf(lr);
      const size_t row = tok0 + mt * 16 + qd * 4 + r;
#pragma unroll
      for (int dt = 0; dt < 4; ++dt)
        O[row * D_ + h * HD_ + dt * 16 + l15] = f2b_fast(o_[mt][dt][r] * inv);
    }
  }
}

// ---------------- orchestration ----------------
extern "C" void kernel_launch(void* const* d_in, const int* in_sizes, int n_in,
                              void* d_out, int out_size, void* d_ws, size_t ws_size,
                              hipStream_t stream)
{
  const float* x   = (const float*)d_in[0];
  const float* Wq  = (const float*)d_in[1];
  const float* bq  = (const float*)d_in[2];
  const float* Wk  = (const float*)d_in[3];
  const float* bk  = (const float*)d_in[4];
  const float* Wv  = (const float*)d_in[5];
  const float* bv  = (const float*)d_in[6];
  const float* Wo  = (const float*)d_in[7];
  const float* bo  = (const float*)d_in[8];
  const float* W1  = (const float*)d_in[9];
  const float* b1  = (const float*)d_in[10];
  const float* W2  = (const float*)d_in[11];
  const float* b2  = (const float*)d_in[12];
  const float* g1  = (const float*)d_in[13];
  const float* be1 = (const float*)d_in[14];
  const float* g2  = (const float*)d_in[15];
  const float* be2 = (const float*)d_in[16];

  // full-M FFN needs 77,079,552 B of workspace; otherwise split (64,496,640 B)
  const bool full = ws_size >= (size_t)77079552;

  char* ws = (char*)d_ws;
  bf16* qk     = (bf16*)(ws + 0);           // QKV gemm -> attn
  bf16* vp     = (bf16*)(ws + 25165824);    // QKV gemm -> attn
  bf16* h1     = (bf16*)(ws + 37748736);    // LN1 -> QKV gemm
  bf16* obuf   = h1;                        // attn -> O-proj (h1 dead)
  bf16* abuf   = (bf16*)(ws + 0);           // O-proj -> LN2 (qk dead)
  bf16* h2     = (bf16*)(ws + (full ? 50331648u : 25165824u));  // LN2 -> FFN1
  bf16* fbuf   = (bf16*)(ws + 0);           // FFN1 -> FFN2 (full: 48 MB; split: 24 MB)
  const size_t wb = full ? 62914560u : 50331648u;
  bf16* wqkv_p = (bf16*)(ws + wb);                    // 3,538,944 B
  bf16* wo_p   = (bf16*)(ws + wb + 3538944u);         // 1,179,648 B
  bf16* w1_p   = (bf16*)(ws + wb + 4718592u);         // 4,718,592 B
  bf16* w2_p   = (bf16*)(ws + wb + 9437184u);         // 4,718,592 B
  float* bqkvf = (float*)(ws + wb + 14155776u);       // 9,216 B

  float* outp = (float*)d_out;

  repack_all<<<dim3(3465), dim3(256), 0, stream>>>(Wq, Wk, Wv, Wo, W1, W2,
                                                   bq, bk, bv,
                                                   wqkv_p, wo_p, w1_p, w2_p, bqkvf);

  ln_x_kernel<<<dim3(BS_/4), dim3(256), 0, stream>>>(x, g1, be1, h1);
  gemm_lds<<<dim3(18, 64), dim3(256), 0, stream>>>(h1, wqkv_p, bqkvf, qk, vp, nullptr, 768, 2304, 0);
  attn_kernel<<<dim3(16, 48), dim3(256), 0, stream>>>(qk, vp, obuf);
  gemm_lds64<<<dim3(12, 64), dim3(256), 0, stream>>>(obuf, wo_p, bo, abuf, nullptr, 768, 768, 1);
  ln_h_kernel<<<dim3(BS_/4), dim3(256), 0, stream>>>(abuf, g2, be2, h2);

  if (full) {
    gemm_lds<<<dim3(24, 64), dim3(256), 0, stream>>>(h2, w1_p, b1, fbuf, nullptr, nullptr, 768, 3072, 2);
    gemm_lds64<<<dim3(12, 64), dim3(256), 0, stream>>>(fbuf, w2_p, b2, nullptr, outp, 3072, 768, 3);
  } else {
    gemm_lds<<<dim3(24, 32), dim3(256), 0, stream>>>(h2, w1_p, b1, fbuf, nullptr, nullptr, 768, 3072, 2);
    gemm_lds64<<<dim3(12, 32), dim3(256), 0, stream>>>(fbuf, w2_p, b2, nullptr, outp, 3072, 768, 3);
    gemm_lds<<<dim3(24, 32), dim3(256), 0, stream>>>(h2 + (size_t)4096 * D_, w1_p, b1, fbuf, nullptr, nullptr, 768, 3072, 2);
    gemm_lds64<<<dim3(12, 32), dim3(256), 0, stream>>>(fbuf, w2_p, b2, nullptr, outp + (size_t)4096 * D_, 3072, 768, 3);
  }
}